// Round 1
// 484.752 us; speedup vs baseline: 1.4817x; 1.4817x over previous
//
#include <hip/hip_runtime.h>
#include <math.h>

#define NN 102400
#define NE 1638400
#define NG 2048
#define KTOP 30
#define NFEAT 97

// ---------- CSR build ----------

// counts + per-edge position in one pass (atomic moved out of fill_kernel)
__global__ void count_kernel(const int* __restrict__ dst, int* __restrict__ counts,
                             int* __restrict__ epos, int ne) {
    int e = blockIdx.x * blockDim.x + threadIdx.x;
    if (e < ne) epos[e] = atomicAdd(&counts[dst[e]], 1);
}

__global__ void dinv_kernel(const int* __restrict__ counts, float* __restrict__ dinv, int n) {
    int i = blockIdx.x * blockDim.x + threadIdx.x;
    if (i < n) dinv[i] = rsqrtf((float)counts[i] + 1.0f);
}

// single-block scan: 1024 threads x 100 elements each (NN = 102400 exactly)
__global__ __launch_bounds__(1024) void scan_kernel(const int* __restrict__ counts,
                                                    int* __restrict__ rowptr) {
    __shared__ int partials[1024];
    int tid = threadIdx.x;
    int base = tid * 100;
    int s = 0;
#pragma unroll 4
    for (int i = 0; i < 100; ++i) s += counts[base + i];
    partials[tid] = s;
    __syncthreads();
    for (int off = 1; off < 1024; off <<= 1) {
        int v = (tid >= off) ? partials[tid - off] : 0;
        __syncthreads();
        partials[tid] += v;
        __syncthreads();
    }
    int run = (tid == 0) ? 0 : partials[tid - 1];
    for (int i = 0; i < 100; ++i) {
        rowptr[base + i] = run;
        run += counts[base + i];
    }
    if (tid == 1023) rowptr[NN] = run;
}

// pure scatter, no atomics, single 4B array (coef computed on the fly in agg)
__global__ void fill_kernel(const int* __restrict__ src, const int* __restrict__ dst,
                            const int* __restrict__ rowptr, const int* __restrict__ epos,
                            int* __restrict__ csr_src, int ne) {
    int e = blockIdx.x * blockDim.x + threadIdx.x;
    if (e >= ne) return;
    csr_src[rowptr[dst[e]] + epos[e]] = src[e];
}

// per-graph start offsets from the sorted batch array (replaces per-block binary search)
__global__ void starts_kernel(const int* __restrict__ batch, int* __restrict__ starts, int n) {
    int i = blockIdx.x * blockDim.x + threadIdx.x;
    if (i >= n) return;
    int c = batch[i];
    int p = (i == 0) ? -1 : batch[i - 1];
    for (int g = p + 1; g <= c; ++g) starts[g] = i;
    if (i == n - 1) {
        for (int g = c + 1; g <= NG; ++g) starts[g] = n;
    }
}

// ---------- dense ----------

template <int FIN, int FOUT>
__global__ void dense_kernel(const float* __restrict__ x, const float* __restrict__ W,
                             float* __restrict__ out, int n_nodes) {
    __shared__ float Ws[FIN * FOUT];
    for (int i = threadIdx.x; i < FIN * FOUT; i += blockDim.x) Ws[i] = W[i];
    __syncthreads();
    int idx = blockIdx.x * blockDim.x + threadIdx.x;
    int n = idx / FOUT, j = idx % FOUT;
    if (n >= n_nodes) return;
    float s = 0.f;
#pragma unroll
    for (int k = 0; k < FIN; ++k) s += x[n * FIN + k] * Ws[k * FOUT + j];
    out[idx] = s;
}

// ---------- fused gather-aggregate + self-term + bias + tanh ----------

__global__ __launch_bounds__(256) void gcn_agg32_kernel(
    const int* __restrict__ rowptr, const int* __restrict__ csr_src,
    const float* __restrict__ htmp, const float* __restrict__ dinv,
    const float* __restrict__ b, float* __restrict__ hout) {
    int idx = blockIdx.x * blockDim.x + threadIdx.x;
    int n = idx >> 5, f = idx & 31;
    if (n >= NN) return;
    int beg = rowptr[n], end = rowptr[n + 1];
    float di = dinv[n];
    float acc = 0.f;
    int i = beg;
    // 4 independent gather chains in flight; sequential adds preserve FP order
    for (; i + 3 < end; i += 4) {
        int s0 = csr_src[i],     s1 = csr_src[i + 1];
        int s2 = csr_src[i + 2], s3 = csr_src[i + 3];
        float c0 = dinv[s0] * di, c1 = dinv[s1] * di;
        float c2 = dinv[s2] * di, c3 = dinv[s3] * di;
        float v0 = htmp[s0 * 32 + f], v1 = htmp[s1 * 32 + f];
        float v2 = htmp[s2 * 32 + f], v3 = htmp[s3 * 32 + f];
        acc += v0 * c0;
        acc += v1 * c1;
        acc += v2 * c2;
        acc += v3 * c3;
    }
    for (; i < end; ++i) {
        int s = csr_src[i];
        acc += htmp[s * 32 + f] * (dinv[s] * di);
    }
    hout[idx] = tanhf(acc + htmp[idx] * di * di + b[f]);
}

__global__ __launch_bounds__(256) void gcn_agg1_kernel(
    const int* __restrict__ rowptr, const int* __restrict__ csr_src,
    const float* __restrict__ htmp, const float* __restrict__ dinv,
    const float* __restrict__ b, float* __restrict__ hout) {
    int n = blockIdx.x * blockDim.x + threadIdx.x;
    if (n >= NN) return;
    int beg = rowptr[n], end = rowptr[n + 1];
    float di = dinv[n];
    float acc = 0.f;
    int i = beg;
    for (; i + 3 < end; i += 4) {
        int s0 = csr_src[i],     s1 = csr_src[i + 1];
        int s2 = csr_src[i + 2], s3 = csr_src[i + 3];
        float c0 = dinv[s0] * di, c1 = dinv[s1] * di;
        float c2 = dinv[s2] * di, c3 = dinv[s3] * di;
        acc += htmp[s0] * c0;
        acc += htmp[s1] * c1;
        acc += htmp[s2] * c2;
        acc += htmp[s3] * c3;
    }
    for (; i < end; ++i) {
        int s = csr_src[i];
        acc += htmp[s] * (dinv[s] * di);
    }
    hout[n] = tanhf(acc + htmp[n] * di * di + b[0]);
}

// ---------- sort-pool + CNN head ----------

__global__ __launch_bounds__(256) void pool_cnn_kernel(
    const float* __restrict__ h1, const float* __restrict__ h2,
    const float* __restrict__ h3, const float* __restrict__ h4,
    const int* __restrict__ starts,
    const float* __restrict__ c1w, const float* __restrict__ c1b,
    const float* __restrict__ c2w, const float* __restrict__ c2b,
    const float* __restrict__ l1w, const float* __restrict__ l1b,
    const float* __restrict__ l2w, const float* __restrict__ l2b,
    float* __restrict__ out) {
    __shared__ float P[KTOP][NFEAT];
    __shared__ float keys[256];
    __shared__ float y1[16][KTOP];
    __shared__ float y2[16][15];
    __shared__ float y3[352];
    __shared__ float z[128];
    int g = blockIdx.x;
    int tid = threadIdx.x;

    int start = starts[g];
    int end = starts[g + 1];
    int cnt = end - start;

    for (int i = tid; i < KTOP * NFEAT; i += 256) (&P[0][0])[i] = 0.f;
    bool fits = (cnt <= 256);
    if (fits) {
        for (int i = tid; i < cnt; i += 256) keys[i] = h4[start + i];
    }
    __syncthreads();

    for (int i = tid; i < cnt; i += 256) {
        float key = fits ? keys[i] : h4[start + i];
        int rank = 0;
        if (fits) {
            for (int j = 0; j < cnt; ++j) {
                float kj = keys[j];
                rank += (kj > key) || (kj == key && j < i);
            }
        } else {
            for (int j = 0; j < cnt; ++j) {
                float kj = h4[start + j];
                rank += (kj > key) || (kj == key && j < i);
            }
        }
        if (rank < KTOP) {
            int node = start + i;
            const float4* r1 = (const float4*)(h1 + node * 32);
            const float4* r2 = (const float4*)(h2 + node * 32);
            const float4* r3 = (const float4*)(h3 + node * 32);
#pragma unroll
            for (int q = 0; q < 8; ++q) {
                float4 v = r1[q];
                P[rank][4 * q + 0] = v.x; P[rank][4 * q + 1] = v.y;
                P[rank][4 * q + 2] = v.z; P[rank][4 * q + 3] = v.w;
            }
#pragma unroll
            for (int q = 0; q < 8; ++q) {
                float4 v = r2[q];
                P[rank][32 + 4 * q + 0] = v.x; P[rank][32 + 4 * q + 1] = v.y;
                P[rank][32 + 4 * q + 2] = v.z; P[rank][32 + 4 * q + 3] = v.w;
            }
#pragma unroll
            for (int q = 0; q < 8; ++q) {
                float4 v = r3[q];
                P[rank][64 + 4 * q + 0] = v.x; P[rank][64 + 4 * q + 1] = v.y;
                P[rank][64 + 4 * q + 2] = v.z; P[rank][64 + 4 * q + 3] = v.w;
            }
            P[rank][96] = key;
        }
    }
    __syncthreads();

    for (int o = tid; o < 16 * KTOP; o += 256) {
        int c = o / KTOP, t = o % KTOP;
        float s = c1b[c];
#pragma unroll
        for (int f = 0; f < 97; ++f) s += c1w[c * 97 + f] * P[t][f];
        y1[c][t] = fmaxf(s, 0.f);
    }
    __syncthreads();

    for (int o = tid; o < 16 * 15; o += 256) {
        int c = o / 15, t = o % 15;
        y2[c][t] = fmaxf(y1[c][2 * t], y1[c][2 * t + 1]);
    }
    __syncthreads();

    for (int o = tid; o < 32 * 11; o += 256) {
        int c = o / 11, t = o % 11;
        float s = c2b[c];
#pragma unroll
        for (int i = 0; i < 16; ++i)
#pragma unroll
            for (int j = 0; j < 5; ++j)
                s += c2w[(c * 16 + i) * 5 + j] * y2[i][t + j];
        y3[o] = fmaxf(s, 0.f);
    }
    __syncthreads();

    for (int o = tid; o < 128; o += 256) {
        float s = l1b[o];
#pragma unroll 4
        for (int i = 0; i < 352; ++i) s += y3[i] * l1w[i * 128 + o];
        z[o] = fmaxf(s, 0.f);
    }
    __syncthreads();

    if (tid == 0) {
        float s = l2b[0];
#pragma unroll 4
        for (int i = 0; i < 128; ++i) s += z[i] * l2w[i];
        out[g] = 1.f / (1.f + expf(-s));
    }
}

extern "C" void kernel_launch(void* const* d_in, const int* in_sizes, int n_in,
                              void* d_out, int out_size, void* d_ws, size_t ws_size,
                              hipStream_t stream) {
    const float* x   = (const float*)d_in[0];
    const int* ei    = (const int*)d_in[1];
    const int* batch = (const int*)d_in[2];
    const float* W1  = (const float*)d_in[3];
    const float* b1  = (const float*)d_in[4];
    const float* W2  = (const float*)d_in[5];
    const float* b2  = (const float*)d_in[6];
    const float* W3  = (const float*)d_in[7];
    const float* b3  = (const float*)d_in[8];
    const float* W4  = (const float*)d_in[9];
    const float* b4  = (const float*)d_in[10];
    const float* c1w = (const float*)d_in[11];
    const float* c1b = (const float*)d_in[12];
    const float* c2w = (const float*)d_in[13];
    const float* c2b = (const float*)d_in[14];
    const float* l1w = (const float*)d_in[15];
    const float* l1b = (const float*)d_in[16];
    const float* l2w = (const float*)d_in[17];
    const float* l2b = (const float*)d_in[18];
    float* out = (float*)d_out;

    const int* srcp = ei;
    const int* dstp = ei + NE;

    // workspace layout
    char* w = (char*)d_ws;
    float* dinv    = (float*)w;                 w += sizeof(float) * NN;
    float* htmp    = (float*)w;                 w += sizeof(float) * NN * 32;
    float* h1      = (float*)w;                 w += sizeof(float) * NN * 32;
    float* h2      = (float*)w;                 w += sizeof(float) * NN * 32;
    float* h3      = (float*)w;                 w += sizeof(float) * NN * 32;
    float* h4      = (float*)w;                 w += sizeof(float) * NN;
    int*   counts  = (int*)w;                   w += sizeof(int) * NN;
    int*   rowptr  = (int*)w;                   w += sizeof(int) * (NN + 1);
    int*   epos    = (int*)w;                   w += sizeof(int) * NE;
    int*   csr_src = (int*)w;                   w += sizeof(int) * NE;
    int*   starts  = (int*)w;                   w += sizeof(int) * (NG + 1);

    // CSR build (reused across all 4 layers)
    hipMemsetAsync(counts, 0, NN * sizeof(int), stream);
    count_kernel<<<NE / 256, 256, 0, stream>>>(dstp, counts, epos, NE);
    dinv_kernel<<<NN / 256, 256, 0, stream>>>(counts, dinv, NN);
    scan_kernel<<<1, 1024, 0, stream>>>(counts, rowptr);
    fill_kernel<<<NE / 256, 256, 0, stream>>>(srcp, dstp, rowptr, epos, csr_src, NE);
    starts_kernel<<<NN / 256, 256, 0, stream>>>(batch, starts, NN);

    // layer 1: 128 -> 32
    dense_kernel<128, 32><<<NN * 32 / 256, 256, 0, stream>>>(x, W1, htmp, NN);
    gcn_agg32_kernel<<<NN * 32 / 256, 256, 0, stream>>>(rowptr, csr_src, htmp, dinv, b1, h1);

    // layer 2: 32 -> 32
    dense_kernel<32, 32><<<NN * 32 / 256, 256, 0, stream>>>(h1, W2, htmp, NN);
    gcn_agg32_kernel<<<NN * 32 / 256, 256, 0, stream>>>(rowptr, csr_src, htmp, dinv, b2, h2);

    // layer 3: 32 -> 32
    dense_kernel<32, 32><<<NN * 32 / 256, 256, 0, stream>>>(h2, W3, htmp, NN);
    gcn_agg32_kernel<<<NN * 32 / 256, 256, 0, stream>>>(rowptr, csr_src, htmp, dinv, b3, h3);

    // layer 4: 32 -> 1
    dense_kernel<32, 1><<<NN / 256, 256, 0, stream>>>(h3, W4, htmp, NN);
    gcn_agg1_kernel<<<NN / 256, 256, 0, stream>>>(rowptr, csr_src, htmp, dinv, b4, h4);

    // fused sort-pool + CNN head
    pool_cnn_kernel<<<NG, 256, 0, stream>>>(h1, h2, h3, h4, starts,
                                            c1w, c1b, c2w, c2b,
                                            l1w, l1b, l2w, l2b, out);
}

// Round 2
// 395.906 us; speedup vs baseline: 1.8142x; 1.2244x over previous
//
#include <hip/hip_runtime.h>
#include <math.h>

#define NN 102400
#define NE 1638400
#define NG 2048
#define KTOP 30
#define NFEAT 97

// ---------- CSR build ----------

__global__ void count_kernel(const int* __restrict__ dst, int* __restrict__ counts,
                             int* __restrict__ epos, int ne) {
    int e = blockIdx.x * blockDim.x + threadIdx.x;
    if (e < ne) epos[e] = atomicAdd(&counts[dst[e]], 1);
}

__global__ void dinv_kernel(const int* __restrict__ counts, float* __restrict__ dinv, int n) {
    int i = blockIdx.x * blockDim.x + threadIdx.x;
    if (i < n) dinv[i] = rsqrtf((float)counts[i] + 1.0f);
}

// single-block scan: 1024 threads x 100 elements each (NN = 102400 exactly)
__global__ __launch_bounds__(1024) void scan_kernel(const int* __restrict__ counts,
                                                    int* __restrict__ rowptr) {
    __shared__ int partials[1024];
    int tid = threadIdx.x;
    int base = tid * 100;
    int s = 0;
#pragma unroll 4
    for (int i = 0; i < 100; ++i) s += counts[base + i];
    partials[tid] = s;
    __syncthreads();
    for (int off = 1; off < 1024; off <<= 1) {
        int v = (tid >= off) ? partials[tid - off] : 0;
        __syncthreads();
        partials[tid] += v;
        __syncthreads();
    }
    int run = (tid == 0) ? 0 : partials[tid - 1];
    for (int i = 0; i < 100; ++i) {
        rowptr[base + i] = run;
        run += counts[base + i];
    }
    if (tid == 1023) rowptr[NN] = run;
}

__global__ void fill_kernel(const int* __restrict__ src, const int* __restrict__ dst,
                            const int* __restrict__ rowptr, const int* __restrict__ epos,
                            int* __restrict__ csr_src, int ne) {
    int e = blockIdx.x * blockDim.x + threadIdx.x;
    if (e >= ne) return;
    csr_src[rowptr[dst[e]] + epos[e]] = src[e];
}

__global__ void starts_kernel(const int* __restrict__ batch, int* __restrict__ starts, int n) {
    int i = blockIdx.x * blockDim.x + threadIdx.x;
    if (i >= n) return;
    int c = batch[i];
    int p = (i == 0) ? -1 : batch[i - 1];
    for (int g = p + 1; g <= c; ++g) starts[g] = i;
    if (i == n - 1) {
        for (int g = c + 1; g <= NG; ++g) starts[g] = n;
    }
}

// ---------- dense: tiled, 2 nodes x 8 outputs per thread ----------
// wave w (tid>>6) owns jb = w*8; lanes q=tid&63 own rows (block*128+q, +64).
// W in LDS: whole wave reads one address per instr -> broadcast, conflict-free.
// x read from global as float4 (each row read exactly once; L1 absorbs line granularity).
// k ascends -> summation order identical to the naive kernel (bit-exact).

template <int FIN>
__global__ __launch_bounds__(256) void dense_tile_kernel(const float* __restrict__ x,
                                                         const float* __restrict__ W,
                                                         float* __restrict__ out) {
    __shared__ float Wsh[FIN * 32];
    for (int i = threadIdx.x; i < FIN * 32; i += 256) Wsh[i] = W[i];
    __syncthreads();
    int jb = (threadIdx.x >> 6) << 3;   // 0,8,16,24
    int q = threadIdx.x & 63;
    int n0 = blockIdx.x * 128 + q;
    int n1 = n0 + 64;
    const float* x0p = x + (size_t)n0 * FIN;
    const float* x1p = x + (size_t)n1 * FIN;
    float acc0[8], acc1[8];
#pragma unroll
    for (int j = 0; j < 8; ++j) { acc0[j] = 0.f; acc1[j] = 0.f; }
#pragma unroll 2
    for (int k = 0; k < FIN; k += 4) {
        float4 xa = *(const float4*)(x0p + k);
        float4 xb = *(const float4*)(x1p + k);
        float xs0[4] = {xa.x, xa.y, xa.z, xa.w};
        float xs1[4] = {xb.x, xb.y, xb.z, xb.w};
#pragma unroll
        for (int kk = 0; kk < 4; ++kk) {
            float4 wlo = *(const float4*)&Wsh[(k + kk) * 32 + jb];
            float4 whi = *(const float4*)&Wsh[(k + kk) * 32 + jb + 4];
            float v0 = xs0[kk], v1 = xs1[kk];
            acc0[0] += v0 * wlo.x; acc0[1] += v0 * wlo.y;
            acc0[2] += v0 * wlo.z; acc0[3] += v0 * wlo.w;
            acc0[4] += v0 * whi.x; acc0[5] += v0 * whi.y;
            acc0[6] += v0 * whi.z; acc0[7] += v0 * whi.w;
            acc1[0] += v1 * wlo.x; acc1[1] += v1 * wlo.y;
            acc1[2] += v1 * wlo.z; acc1[3] += v1 * wlo.w;
            acc1[4] += v1 * whi.x; acc1[5] += v1 * whi.y;
            acc1[6] += v1 * whi.z; acc1[7] += v1 * whi.w;
        }
    }
    float4 o0 = {acc0[0], acc0[1], acc0[2], acc0[3]};
    float4 o1 = {acc0[4], acc0[5], acc0[6], acc0[7]};
    float4 o2 = {acc1[0], acc1[1], acc1[2], acc1[3]};
    float4 o3 = {acc1[4], acc1[5], acc1[6], acc1[7]};
    *(float4*)&out[(size_t)n0 * 32 + jb] = o0;
    *(float4*)&out[(size_t)n0 * 32 + jb + 4] = o1;
    *(float4*)&out[(size_t)n1 * 32 + jb] = o2;
    *(float4*)&out[(size_t)n1 * 32 + jb + 4] = o3;
}

// 32 -> 1 dense, float4 row loads
__global__ __launch_bounds__(256) void dense4_kernel(const float* __restrict__ x,
                                                     const float* __restrict__ W,
                                                     float* __restrict__ out) {
    __shared__ float Ws[32];
    if (threadIdx.x < 32) Ws[threadIdx.x] = W[threadIdx.x];
    __syncthreads();
    int n = blockIdx.x * 256 + threadIdx.x;
    if (n >= NN) return;
    const float4* xr = (const float4*)(x + (size_t)n * 32);
    float s = 0.f;
#pragma unroll
    for (int qq = 0; qq < 8; ++qq) {
        float4 v = xr[qq];
        float4 wv = *(const float4*)&Ws[qq * 4];
        s += v.x * wv.x; s += v.y * wv.y; s += v.z * wv.z; s += v.w * wv.w;
    }
    out[n] = s;
}

// ---------- fused gather-aggregate + self-term + bias + tanh ----------
// 8 lanes per node, each lane owns 4 consecutive features (float4 gathers).
// Per-feature edge accumulation order identical to the scalar version.

__global__ __launch_bounds__(256) void gcn_agg32v_kernel(
    const int* __restrict__ rowptr, const int* __restrict__ csr_src,
    const float* __restrict__ htmp, const float* __restrict__ dinv,
    const float* __restrict__ b, float* __restrict__ hout) {
    int idx = blockIdx.x * 256 + threadIdx.x;
    int n = idx >> 3, fg = (idx & 7) << 2;
    if (n >= NN) return;
    int beg = rowptr[n], end = rowptr[n + 1];
    float di = dinv[n];
    float4 acc = {0.f, 0.f, 0.f, 0.f};
    int i = beg;
    for (; i + 3 < end; i += 4) {
        int s0 = csr_src[i], s1 = csr_src[i + 1];
        int s2 = csr_src[i + 2], s3 = csr_src[i + 3];
        float c0 = dinv[s0] * di, c1 = dinv[s1] * di;
        float c2 = dinv[s2] * di, c3 = dinv[s3] * di;
        float4 v0 = *(const float4*)&htmp[(size_t)s0 * 32 + fg];
        float4 v1 = *(const float4*)&htmp[(size_t)s1 * 32 + fg];
        float4 v2 = *(const float4*)&htmp[(size_t)s2 * 32 + fg];
        float4 v3 = *(const float4*)&htmp[(size_t)s3 * 32 + fg];
        acc.x += v0.x * c0; acc.y += v0.y * c0; acc.z += v0.z * c0; acc.w += v0.w * c0;
        acc.x += v1.x * c1; acc.y += v1.y * c1; acc.z += v1.z * c1; acc.w += v1.w * c1;
        acc.x += v2.x * c2; acc.y += v2.y * c2; acc.z += v2.z * c2; acc.w += v2.w * c2;
        acc.x += v3.x * c3; acc.y += v3.y * c3; acc.z += v3.z * c3; acc.w += v3.w * c3;
    }
    for (; i < end; ++i) {
        int s = csr_src[i];
        float c = dinv[s] * di;
        float4 v = *(const float4*)&htmp[(size_t)s * 32 + fg];
        acc.x += v.x * c; acc.y += v.y * c; acc.z += v.z * c; acc.w += v.w * c;
    }
    float dd = di * di;
    float4 hs = *(const float4*)&htmp[(size_t)n * 32 + fg];
    float4 bb = *(const float4*)&b[fg];
    float4 o;
    o.x = tanhf(acc.x + hs.x * dd + bb.x);
    o.y = tanhf(acc.y + hs.y * dd + bb.y);
    o.z = tanhf(acc.z + hs.z * dd + bb.z);
    o.w = tanhf(acc.w + hs.w * dd + bb.w);
    *(float4*)&hout[(size_t)n * 32 + fg] = o;
}

__global__ __launch_bounds__(256) void gcn_agg1_kernel(
    const int* __restrict__ rowptr, const int* __restrict__ csr_src,
    const float* __restrict__ htmp, const float* __restrict__ dinv,
    const float* __restrict__ b, float* __restrict__ hout) {
    int n = blockIdx.x * blockDim.x + threadIdx.x;
    if (n >= NN) return;
    int beg = rowptr[n], end = rowptr[n + 1];
    float di = dinv[n];
    float acc = 0.f;
    int i = beg;
    for (; i + 3 < end; i += 4) {
        int s0 = csr_src[i], s1 = csr_src[i + 1];
        int s2 = csr_src[i + 2], s3 = csr_src[i + 3];
        float c0 = dinv[s0] * di, c1 = dinv[s1] * di;
        float c2 = dinv[s2] * di, c3 = dinv[s3] * di;
        acc += htmp[s0] * c0;
        acc += htmp[s1] * c1;
        acc += htmp[s2] * c2;
        acc += htmp[s3] * c3;
    }
    for (; i < end; ++i) {
        int s = csr_src[i];
        acc += htmp[s] * (dinv[s] * di);
    }
    hout[n] = tanhf(acc + htmp[n] * di * di + b[0]);
}

// ---------- sort-pool + CNN head ----------

#define PSTR 100  // padded row stride for P and staged c1w (float4-aligned)

__global__ __launch_bounds__(256) void pool_cnn_kernel(
    const float* __restrict__ h1, const float* __restrict__ h2,
    const float* __restrict__ h3, const float* __restrict__ h4,
    const int* __restrict__ starts,
    const float* __restrict__ c1w, const float* __restrict__ c1b,
    const float* __restrict__ c2w, const float* __restrict__ c2b,
    const float* __restrict__ l1w, const float* __restrict__ l1b,
    const float* __restrict__ l2w, const float* __restrict__ l2b,
    float* __restrict__ out) {
    __shared__ float P[KTOP][PSTR];   // 3000 floats; aliased by y2/y3/z after conv1
    __shared__ float CW[16 * PSTR];   // staged c1w, padded
    __shared__ float KY[480];         // keys (first 256) ∪ y1[16][30]
    float* keys = KY;
    float* y2 = &P[0][0];             // 240 floats (written after P is dead)
    float* y3 = &P[0][0] + 240;       // 352 floats
    float* z  = &P[0][0] + 592;       // 128 floats
    int g = blockIdx.x;
    int tid = threadIdx.x;

    int start = starts[g];
    int end = starts[g + 1];
    int cnt = end - start;

    for (int i = tid; i < KTOP * PSTR; i += 256) (&P[0][0])[i] = 0.f;
    for (int i = tid; i < 16 * 97; i += 256) {
        int c = i / 97, f = i % 97;
        CW[c * PSTR + f] = c1w[i];
    }
    bool fits = (cnt <= 256);
    if (fits) {
        for (int i = tid; i < cnt; i += 256) keys[i] = h4[start + i];
    }
    __syncthreads();

    for (int i = tid; i < cnt; i += 256) {
        float key = fits ? keys[i] : h4[start + i];
        int rank = 0;
        if (fits) {
            for (int j = 0; j < cnt; ++j) {
                float kj = keys[j];
                rank += (kj > key) || (kj == key && j < i);
            }
        } else {
            for (int j = 0; j < cnt; ++j) {
                float kj = h4[start + j];
                rank += (kj > key) || (kj == key && j < i);
            }
        }
        if (rank < KTOP) {
            int node = start + i;
            const float4* r1 = (const float4*)(h1 + (size_t)node * 32);
            const float4* r2 = (const float4*)(h2 + (size_t)node * 32);
            const float4* r3 = (const float4*)(h3 + (size_t)node * 32);
#pragma unroll
            for (int q = 0; q < 8; ++q) *(float4*)&P[rank][4 * q] = r1[q];
#pragma unroll
            for (int q = 0; q < 8; ++q) *(float4*)&P[rank][32 + 4 * q] = r2[q];
#pragma unroll
            for (int q = 0; q < 8; ++q) *(float4*)&P[rank][64 + 4 * q] = r3[q];
            P[rank][96] = key;
        }
    }
    __syncthreads();

    // conv1: float4 LDS reads of P and staged weights (f ascending -> same order)
    for (int o = tid; o < 16 * KTOP; o += 256) {
        int c = o / KTOP, t = o % KTOP;
        float s = c1b[c];
        const float* Pr = &P[t][0];
        const float* Wr = &CW[c * PSTR];
#pragma unroll
        for (int f4 = 0; f4 < 24; ++f4) {
            float4 pv = *(const float4*)(Pr + 4 * f4);
            float4 wv = *(const float4*)(Wr + 4 * f4);
            s += wv.x * pv.x; s += wv.y * pv.y; s += wv.z * pv.z; s += wv.w * pv.w;
        }
        s += Wr[96] * Pr[96];
        KY[c * KTOP + t] = fmaxf(s, 0.f);   // y1
    }
    __syncthreads();

    for (int o = tid; o < 16 * 15; o += 256) {
        int c = o / 15, t = o % 15;
        y2[o] = fmaxf(KY[c * KTOP + 2 * t], KY[c * KTOP + 2 * t + 1]);
    }
    __syncthreads();

    for (int o = tid; o < 32 * 11; o += 256) {
        int c = o / 11, t = o % 11;
        float s = c2b[c];
#pragma unroll
        for (int i = 0; i < 16; ++i)
#pragma unroll
            for (int j = 0; j < 5; ++j)
                s += c2w[(c * 16 + i) * 5 + j] * y2[i * 15 + t + j];
        y3[o] = fmaxf(s, 0.f);
    }
    __syncthreads();

    for (int o = tid; o < 128; o += 256) {
        float s = l1b[o];
#pragma unroll 16
        for (int i = 0; i < 352; ++i) s += y3[i] * l1w[i * 128 + o];
        z[o] = fmaxf(s, 0.f);
    }
    __syncthreads();

    if (tid == 0) {
        float s = l2b[0];
#pragma unroll 4
        for (int i = 0; i < 128; ++i) s += z[i] * l2w[i];
        out[g] = 1.f / (1.f + expf(-s));
    }
}

extern "C" void kernel_launch(void* const* d_in, const int* in_sizes, int n_in,
                              void* d_out, int out_size, void* d_ws, size_t ws_size,
                              hipStream_t stream) {
    const float* x   = (const float*)d_in[0];
    const int* ei    = (const int*)d_in[1];
    const int* batch = (const int*)d_in[2];
    const float* W1  = (const float*)d_in[3];
    const float* b1  = (const float*)d_in[4];
    const float* W2  = (const float*)d_in[5];
    const float* b2  = (const float*)d_in[6];
    const float* W3  = (const float*)d_in[7];
    const float* b3  = (const float*)d_in[8];
    const float* W4  = (const float*)d_in[9];
    const float* b4  = (const float*)d_in[10];
    const float* c1w = (const float*)d_in[11];
    const float* c1b = (const float*)d_in[12];
    const float* c2w = (const float*)d_in[13];
    const float* c2b = (const float*)d_in[14];
    const float* l1w = (const float*)d_in[15];
    const float* l1b = (const float*)d_in[16];
    const float* l2w = (const float*)d_in[17];
    const float* l2b = (const float*)d_in[18];
    float* out = (float*)d_out;

    const int* srcp = ei;
    const int* dstp = ei + NE;

    // workspace layout
    char* w = (char*)d_ws;
    float* dinv    = (float*)w;                 w += sizeof(float) * NN;
    float* htmp    = (float*)w;                 w += sizeof(float) * NN * 32;
    float* h1      = (float*)w;                 w += sizeof(float) * NN * 32;
    float* h2      = (float*)w;                 w += sizeof(float) * NN * 32;
    float* h3      = (float*)w;                 w += sizeof(float) * NN * 32;
    float* h4      = (float*)w;                 w += sizeof(float) * NN;
    int*   counts  = (int*)w;                   w += sizeof(int) * NN;
    int*   rowptr  = (int*)w;                   w += sizeof(int) * (NN + 1);
    int*   epos    = (int*)w;                   w += sizeof(int) * NE;
    int*   csr_src = (int*)w;                   w += sizeof(int) * NE;
    int*   starts  = (int*)w;                   w += sizeof(int) * (NG + 1);

    // CSR build (reused across all 4 layers)
    hipMemsetAsync(counts, 0, NN * sizeof(int), stream);
    count_kernel<<<NE / 256, 256, 0, stream>>>(dstp, counts, epos, NE);
    dinv_kernel<<<NN / 256, 256, 0, stream>>>(counts, dinv, NN);
    scan_kernel<<<1, 1024, 0, stream>>>(counts, rowptr);
    fill_kernel<<<NE / 256, 256, 0, stream>>>(srcp, dstp, rowptr, epos, csr_src, NE);
    starts_kernel<<<NN / 256, 256, 0, stream>>>(batch, starts, NN);

    // layer 1: 128 -> 32
    dense_tile_kernel<128><<<NN / 128, 256, 0, stream>>>(x, W1, htmp);
    gcn_agg32v_kernel<<<NN * 8 / 256, 256, 0, stream>>>(rowptr, csr_src, htmp, dinv, b1, h1);

    // layer 2: 32 -> 32
    dense_tile_kernel<32><<<NN / 128, 256, 0, stream>>>(h1, W2, htmp);
    gcn_agg32v_kernel<<<NN * 8 / 256, 256, 0, stream>>>(rowptr, csr_src, htmp, dinv, b2, h2);

    // layer 3: 32 -> 32
    dense_tile_kernel<32><<<NN / 128, 256, 0, stream>>>(h2, W3, htmp);
    gcn_agg32v_kernel<<<NN * 8 / 256, 256, 0, stream>>>(rowptr, csr_src, htmp, dinv, b3, h3);

    // layer 4: 32 -> 1
    dense4_kernel<<<NN / 256, 256, 0, stream>>>(h3, W4, htmp);
    gcn_agg1_kernel<<<NN / 256, 256, 0, stream>>>(rowptr, csr_src, htmp, dinv, b4, h4);

    // fused sort-pool + CNN head
    pool_cnn_kernel<<<NG, 256, 0, stream>>>(h1, h2, h3, h4, starts,
                                            c1w, c1b, c2w, c2b,
                                            l1w, l1b, l2w, l2b, out);
}

// Round 3
// 352.445 us; speedup vs baseline: 2.0380x; 1.1233x over previous
//
#include <hip/hip_runtime.h>
#include <math.h>

#define NN 102400
#define NE 1638400
#define NG 2048
#define KTOP 30
#define NFEAT 97

// ---------- CSR build ----------

// 8 edges per thread -> 8 independent atomic RMW chains in flight per thread.
// Chunks are grid-strided so each 64-lane wave's loads stay coalesced.
__global__ __launch_bounds__(256) void count_kernel(const int* __restrict__ dst,
                                                    int* __restrict__ counts,
                                                    int* __restrict__ epos) {
    const int S = NE / 8;  // 204800
    int t = blockIdx.x * 256 + threadIdx.x;
    int d[8], p[8];
#pragma unroll
    for (int k = 0; k < 8; ++k) d[k] = dst[t + k * S];
#pragma unroll
    for (int k = 0; k < 8; ++k) p[k] = atomicAdd(&counts[d[k]], 1);
#pragma unroll
    for (int k = 0; k < 8; ++k) epos[t + k * S] = p[k];
}

// parallel scan, pass A: per-block (256-wide) sums + fused dinv
__global__ __launch_bounds__(256) void scanA_kernel(const int* __restrict__ counts,
                                                    float* __restrict__ dinv,
                                                    int* __restrict__ bsum) {
    __shared__ int red[256];
    int tid = threadIdx.x;
    int i = blockIdx.x * 256 + tid;
    int c = counts[i];
    dinv[i] = rsqrtf((float)c + 1.0f);
    red[tid] = c;
    __syncthreads();
    for (int off = 128; off >= 1; off >>= 1) {
        if (tid < off) red[tid] += red[tid + off];
        __syncthreads();
    }
    if (tid == 0) bsum[blockIdx.x] = red[0];
}

// parallel scan, pass B: each of 400 blocks computes its base (redundant small
// reduce over bsum) + intra-block exclusive scan -> rowptr
__global__ __launch_bounds__(256) void scanB_kernel(const int* __restrict__ counts,
                                                    const int* __restrict__ bsum,
                                                    int* __restrict__ rowptr) {
    __shared__ int tmp[256];
    int b = blockIdx.x, tid = threadIdx.x;
    const int NB = NN / 256;  // 400
    // base = sum of bsum[0..b)
    int v = 0;
    if (tid < b) v += bsum[tid];
    if (tid + 256 < b) v += bsum[tid + 256];
    tmp[tid] = v;
    __syncthreads();
    for (int off = 128; off >= 1; off >>= 1) {
        if (tid < off) tmp[tid] += tmp[tid + off];
        __syncthreads();
    }
    int base = tmp[0];
    __syncthreads();
    // intra-block inclusive scan of counts
    int c = counts[b * 256 + tid];
    tmp[tid] = c;
    __syncthreads();
    for (int off = 1; off < 256; off <<= 1) {
        int u = (tid >= off) ? tmp[tid - off] : 0;
        __syncthreads();
        tmp[tid] += u;
        __syncthreads();
    }
    rowptr[b * 256 + tid] = base + tmp[tid] - c;  // exclusive
    if (b == NB - 1 && tid == 255) rowptr[NN] = base + tmp[255];
}

// pure scatter, 8 edges per thread (8 independent dst->rowptr gather chains)
__global__ __launch_bounds__(256) void fill_kernel(const int* __restrict__ src,
                                                   const int* __restrict__ dst,
                                                   const int* __restrict__ rowptr,
                                                   const int* __restrict__ epos,
                                                   int* __restrict__ csr_src) {
    const int S = NE / 8;
    int t = blockIdx.x * 256 + threadIdx.x;
    int d[8], p[8], s[8], rp[8];
#pragma unroll
    for (int k = 0; k < 8; ++k) d[k] = dst[t + k * S];
#pragma unroll
    for (int k = 0; k < 8; ++k) p[k] = epos[t + k * S];
#pragma unroll
    for (int k = 0; k < 8; ++k) s[k] = src[t + k * S];
#pragma unroll
    for (int k = 0; k < 8; ++k) rp[k] = rowptr[d[k]];
#pragma unroll
    for (int k = 0; k < 8; ++k) csr_src[rp[k] + p[k]] = s[k];
}

__global__ void starts_kernel(const int* __restrict__ batch, int* __restrict__ starts, int n) {
    int i = blockIdx.x * blockDim.x + threadIdx.x;
    if (i >= n) return;
    int c = batch[i];
    int p = (i == 0) ? -1 : batch[i - 1];
    for (int g = p + 1; g <= c; ++g) starts[g] = i;
    if (i == n - 1) {
        for (int g = c + 1; g <= NG; ++g) starts[g] = n;
    }
}

// ---------- dense: tiled, 2 nodes x 8 outputs per thread ----------

template <int FIN>
__global__ __launch_bounds__(256) void dense_tile_kernel(const float* __restrict__ x,
                                                         const float* __restrict__ W,
                                                         float* __restrict__ out) {
    __shared__ float Wsh[FIN * 32];
    for (int i = threadIdx.x; i < FIN * 32; i += 256) Wsh[i] = W[i];
    __syncthreads();
    int jb = (threadIdx.x >> 6) << 3;   // 0,8,16,24
    int q = threadIdx.x & 63;
    int n0 = blockIdx.x * 128 + q;
    int n1 = n0 + 64;
    const float* x0p = x + (size_t)n0 * FIN;
    const float* x1p = x + (size_t)n1 * FIN;
    float acc0[8], acc1[8];
#pragma unroll
    for (int j = 0; j < 8; ++j) { acc0[j] = 0.f; acc1[j] = 0.f; }
#pragma unroll 2
    for (int k = 0; k < FIN; k += 4) {
        float4 xa = *(const float4*)(x0p + k);
        float4 xb = *(const float4*)(x1p + k);
        float xs0[4] = {xa.x, xa.y, xa.z, xa.w};
        float xs1[4] = {xb.x, xb.y, xb.z, xb.w};
#pragma unroll
        for (int kk = 0; kk < 4; ++kk) {
            float4 wlo = *(const float4*)&Wsh[(k + kk) * 32 + jb];
            float4 whi = *(const float4*)&Wsh[(k + kk) * 32 + jb + 4];
            float v0 = xs0[kk], v1 = xs1[kk];
            acc0[0] += v0 * wlo.x; acc0[1] += v0 * wlo.y;
            acc0[2] += v0 * wlo.z; acc0[3] += v0 * wlo.w;
            acc0[4] += v0 * whi.x; acc0[5] += v0 * whi.y;
            acc0[6] += v0 * whi.z; acc0[7] += v0 * whi.w;
            acc1[0] += v1 * wlo.x; acc1[1] += v1 * wlo.y;
            acc1[2] += v1 * wlo.z; acc1[3] += v1 * wlo.w;
            acc1[4] += v1 * whi.x; acc1[5] += v1 * whi.y;
            acc1[6] += v1 * whi.z; acc1[7] += v1 * whi.w;
        }
    }
    float4 o0 = {acc0[0], acc0[1], acc0[2], acc0[3]};
    float4 o1 = {acc0[4], acc0[5], acc0[6], acc0[7]};
    float4 o2 = {acc1[0], acc1[1], acc1[2], acc1[3]};
    float4 o3 = {acc1[4], acc1[5], acc1[6], acc1[7]};
    *(float4*)&out[(size_t)n0 * 32 + jb] = o0;
    *(float4*)&out[(size_t)n0 * 32 + jb + 4] = o1;
    *(float4*)&out[(size_t)n1 * 32 + jb] = o2;
    *(float4*)&out[(size_t)n1 * 32 + jb + 4] = o3;
}

// 32 -> 1 dense, float4 row loads
__global__ __launch_bounds__(256) void dense4_kernel(const float* __restrict__ x,
                                                     const float* __restrict__ W,
                                                     float* __restrict__ out) {
    __shared__ float Ws[32];
    if (threadIdx.x < 32) Ws[threadIdx.x] = W[threadIdx.x];
    __syncthreads();
    int n = blockIdx.x * 256 + threadIdx.x;
    if (n >= NN) return;
    const float4* xr = (const float4*)(x + (size_t)n * 32);
    float s = 0.f;
#pragma unroll
    for (int qq = 0; qq < 8; ++qq) {
        float4 v = xr[qq];
        float4 wv = *(const float4*)&Ws[qq * 4];
        s += v.x * wv.x; s += v.y * wv.y; s += v.z * wv.z; s += v.w * wv.w;
    }
    out[n] = s;
}

// ---------- fused gather-aggregate + self-term + bias + tanh ----------
// 8 lanes per node, float4 per lane; 8-deep independent gather chains.
// Accumulation strictly ascends i into one accumulator -> bit-identical order.

__global__ __launch_bounds__(256) void gcn_agg32v_kernel(
    const int* __restrict__ rowptr, const int* __restrict__ csr_src,
    const float* __restrict__ htmp, const float* __restrict__ dinv,
    const float* __restrict__ b, float* __restrict__ hout) {
    int idx = blockIdx.x * 256 + threadIdx.x;
    int n = idx >> 3, fg = (idx & 7) << 2;
    if (n >= NN) return;
    int beg = rowptr[n], end = rowptr[n + 1];
    float di = dinv[n];
    float4 acc = {0.f, 0.f, 0.f, 0.f};
    int i = beg;
    for (; i + 7 < end; i += 8) {
        int s[8];
#pragma unroll
        for (int k = 0; k < 8; ++k) s[k] = csr_src[i + k];
        float c[8];
#pragma unroll
        for (int k = 0; k < 8; ++k) c[k] = dinv[s[k]] * di;
        float4 v[8];
#pragma unroll
        for (int k = 0; k < 8; ++k) v[k] = *(const float4*)&htmp[(size_t)s[k] * 32 + fg];
#pragma unroll
        for (int k = 0; k < 8; ++k) {
            acc.x += v[k].x * c[k]; acc.y += v[k].y * c[k];
            acc.z += v[k].z * c[k]; acc.w += v[k].w * c[k];
        }
    }
    for (; i + 3 < end; i += 4) {
        int s0 = csr_src[i], s1 = csr_src[i + 1];
        int s2 = csr_src[i + 2], s3 = csr_src[i + 3];
        float c0 = dinv[s0] * di, c1 = dinv[s1] * di;
        float c2 = dinv[s2] * di, c3 = dinv[s3] * di;
        float4 v0 = *(const float4*)&htmp[(size_t)s0 * 32 + fg];
        float4 v1 = *(const float4*)&htmp[(size_t)s1 * 32 + fg];
        float4 v2 = *(const float4*)&htmp[(size_t)s2 * 32 + fg];
        float4 v3 = *(const float4*)&htmp[(size_t)s3 * 32 + fg];
        acc.x += v0.x * c0; acc.y += v0.y * c0; acc.z += v0.z * c0; acc.w += v0.w * c0;
        acc.x += v1.x * c1; acc.y += v1.y * c1; acc.z += v1.z * c1; acc.w += v1.w * c1;
        acc.x += v2.x * c2; acc.y += v2.y * c2; acc.z += v2.z * c2; acc.w += v2.w * c2;
        acc.x += v3.x * c3; acc.y += v3.y * c3; acc.z += v3.z * c3; acc.w += v3.w * c3;
    }
    for (; i < end; ++i) {
        int s = csr_src[i];
        float c = dinv[s] * di;
        float4 v = *(const float4*)&htmp[(size_t)s * 32 + fg];
        acc.x += v.x * c; acc.y += v.y * c; acc.z += v.z * c; acc.w += v.w * c;
    }
    float dd = di * di;
    float4 hs = *(const float4*)&htmp[(size_t)n * 32 + fg];
    float4 bb = *(const float4*)&b[fg];
    float4 o;
    o.x = tanhf(acc.x + hs.x * dd + bb.x);
    o.y = tanhf(acc.y + hs.y * dd + bb.y);
    o.z = tanhf(acc.z + hs.z * dd + bb.z);
    o.w = tanhf(acc.w + hs.w * dd + bb.w);
    *(float4*)&hout[(size_t)n * 32 + fg] = o;
}

__global__ __launch_bounds__(256) void gcn_agg1_kernel(
    const int* __restrict__ rowptr, const int* __restrict__ csr_src,
    const float* __restrict__ htmp, const float* __restrict__ dinv,
    const float* __restrict__ b, float* __restrict__ hout) {
    int n = blockIdx.x * blockDim.x + threadIdx.x;
    if (n >= NN) return;
    int beg = rowptr[n], end = rowptr[n + 1];
    float di = dinv[n];
    float acc = 0.f;
    int i = beg;
    for (; i + 7 < end; i += 8) {
        int s[8];
#pragma unroll
        for (int k = 0; k < 8; ++k) s[k] = csr_src[i + k];
        float c[8], v[8];
#pragma unroll
        for (int k = 0; k < 8; ++k) c[k] = dinv[s[k]] * di;
#pragma unroll
        for (int k = 0; k < 8; ++k) v[k] = htmp[s[k]];
#pragma unroll
        for (int k = 0; k < 8; ++k) acc += v[k] * c[k];
    }
    for (; i + 3 < end; i += 4) {
        int s0 = csr_src[i], s1 = csr_src[i + 1];
        int s2 = csr_src[i + 2], s3 = csr_src[i + 3];
        float c0 = dinv[s0] * di, c1 = dinv[s1] * di;
        float c2 = dinv[s2] * di, c3 = dinv[s3] * di;
        acc += htmp[s0] * c0;
        acc += htmp[s1] * c1;
        acc += htmp[s2] * c2;
        acc += htmp[s3] * c3;
    }
    for (; i < end; ++i) {
        int s = csr_src[i];
        acc += htmp[s] * (dinv[s] * di);
    }
    hout[n] = tanhf(acc + htmp[n] * di * di + b[0]);
}

// ---------- sort-pool + CNN head ----------

#define PSTR 100  // padded row stride for P and staged c1w (float4-aligned)

__global__ __launch_bounds__(256) void pool_cnn_kernel(
    const float* __restrict__ h1, const float* __restrict__ h2,
    const float* __restrict__ h3, const float* __restrict__ h4,
    const int* __restrict__ starts,
    const float* __restrict__ c1w, const float* __restrict__ c1b,
    const float* __restrict__ c2w, const float* __restrict__ c2b,
    const float* __restrict__ l1w, const float* __restrict__ l1b,
    const float* __restrict__ l2w, const float* __restrict__ l2b,
    float* __restrict__ out) {
    __shared__ float P[KTOP][PSTR];   // 3000 floats; aliased by y2/y3/z after conv1
    __shared__ float CW[16 * PSTR];   // staged c1w, padded
    __shared__ float KY[480];         // keys (first 256) ∪ y1[16][30]
    float* keys = KY;
    float* y2 = &P[0][0];             // 240 floats (written after P is dead)
    float* y3 = &P[0][0] + 240;       // 352 floats
    float* z  = &P[0][0] + 592;       // 128 floats
    int g = blockIdx.x;
    int tid = threadIdx.x;

    int start = starts[g];
    int end = starts[g + 1];
    int cnt = end - start;

    for (int i = tid; i < KTOP * PSTR; i += 256) (&P[0][0])[i] = 0.f;
    for (int i = tid; i < 16 * 97; i += 256) {
        int c = i / 97, f = i % 97;
        CW[c * PSTR + f] = c1w[i];
    }
    bool fits = (cnt <= 256);
    if (fits) {
        for (int i = tid; i < cnt; i += 256) keys[i] = h4[start + i];
    }
    __syncthreads();

    for (int i = tid; i < cnt; i += 256) {
        float key = fits ? keys[i] : h4[start + i];
        int rank = 0;
        if (fits) {
            for (int j = 0; j < cnt; ++j) {
                float kj = keys[j];
                rank += (kj > key) || (kj == key && j < i);
            }
        } else {
            for (int j = 0; j < cnt; ++j) {
                float kj = h4[start + j];
                rank += (kj > key) || (kj == key && j < i);
            }
        }
        if (rank < KTOP) {
            int node = start + i;
            const float4* r1 = (const float4*)(h1 + (size_t)node * 32);
            const float4* r2 = (const float4*)(h2 + (size_t)node * 32);
            const float4* r3 = (const float4*)(h3 + (size_t)node * 32);
#pragma unroll
            for (int q = 0; q < 8; ++q) *(float4*)&P[rank][4 * q] = r1[q];
#pragma unroll
            for (int q = 0; q < 8; ++q) *(float4*)&P[rank][32 + 4 * q] = r2[q];
#pragma unroll
            for (int q = 0; q < 8; ++q) *(float4*)&P[rank][64 + 4 * q] = r3[q];
            P[rank][96] = key;
        }
    }
    __syncthreads();

    // conv1: float4 LDS reads of P and staged weights (f ascending -> same order)
    for (int o = tid; o < 16 * KTOP; o += 256) {
        int c = o / KTOP, t = o % KTOP;
        float s = c1b[c];
        const float* Pr = &P[t][0];
        const float* Wr = &CW[c * PSTR];
#pragma unroll
        for (int f4 = 0; f4 < 24; ++f4) {
            float4 pv = *(const float4*)(Pr + 4 * f4);
            float4 wv = *(const float4*)(Wr + 4 * f4);
            s += wv.x * pv.x; s += wv.y * pv.y; s += wv.z * pv.z; s += wv.w * pv.w;
        }
        s += Wr[96] * Pr[96];
        KY[c * KTOP + t] = fmaxf(s, 0.f);   // y1
    }
    __syncthreads();

    for (int o = tid; o < 16 * 15; o += 256) {
        int c = o / 15, t = o % 15;
        y2[o] = fmaxf(KY[c * KTOP + 2 * t], KY[c * KTOP + 2 * t + 1]);
    }
    __syncthreads();

    for (int o = tid; o < 32 * 11; o += 256) {
        int c = o / 11, t = o % 11;
        float s = c2b[c];
#pragma unroll
        for (int i = 0; i < 16; ++i)
#pragma unroll
            for (int j = 0; j < 5; ++j)
                s += c2w[(c * 16 + i) * 5 + j] * y2[i * 15 + t + j];
        y3[o] = fmaxf(s, 0.f);
    }
    __syncthreads();

    for (int o = tid; o < 128; o += 256) {
        float s = l1b[o];
#pragma unroll 16
        for (int i = 0; i < 352; ++i) s += y3[i] * l1w[i * 128 + o];
        z[o] = fmaxf(s, 0.f);
    }
    __syncthreads();

    if (tid == 0) {
        float s = l2b[0];
#pragma unroll 4
        for (int i = 0; i < 128; ++i) s += z[i] * l2w[i];
        out[g] = 1.f / (1.f + expf(-s));
    }
}

extern "C" void kernel_launch(void* const* d_in, const int* in_sizes, int n_in,
                              void* d_out, int out_size, void* d_ws, size_t ws_size,
                              hipStream_t stream) {
    const float* x   = (const float*)d_in[0];
    const int* ei    = (const int*)d_in[1];
    const int* batch = (const int*)d_in[2];
    const float* W1  = (const float*)d_in[3];
    const float* b1  = (const float*)d_in[4];
    const float* W2  = (const float*)d_in[5];
    const float* b2  = (const float*)d_in[6];
    const float* W3  = (const float*)d_in[7];
    const float* b3  = (const float*)d_in[8];
    const float* W4  = (const float*)d_in[9];
    const float* b4  = (const float*)d_in[10];
    const float* c1w = (const float*)d_in[11];
    const float* c1b = (const float*)d_in[12];
    const float* c2w = (const float*)d_in[13];
    const float* c2b = (const float*)d_in[14];
    const float* l1w = (const float*)d_in[15];
    const float* l1b = (const float*)d_in[16];
    const float* l2w = (const float*)d_in[17];
    const float* l2b = (const float*)d_in[18];
    float* out = (float*)d_out;

    const int* srcp = ei;
    const int* dstp = ei + NE;

    // workspace layout
    char* w = (char*)d_ws;
    float* dinv    = (float*)w;                 w += sizeof(float) * NN;
    float* htmp    = (float*)w;                 w += sizeof(float) * NN * 32;
    float* h1      = (float*)w;                 w += sizeof(float) * NN * 32;
    float* h2      = (float*)w;                 w += sizeof(float) * NN * 32;
    float* h3      = (float*)w;                 w += sizeof(float) * NN * 32;
    float* h4      = (float*)w;                 w += sizeof(float) * NN;
    int*   counts  = (int*)w;                   w += sizeof(int) * NN;
    int*   rowptr  = (int*)w;                   w += sizeof(int) * (NN + 1);
    int*   epos    = (int*)w;                   w += sizeof(int) * NE;
    int*   csr_src = (int*)w;                   w += sizeof(int) * NE;
    int*   bsum    = (int*)w;                   w += sizeof(int) * (NN / 256);
    int*   starts  = (int*)w;                   w += sizeof(int) * (NG + 1);

    // CSR build (reused across all 4 layers)
    hipMemsetAsync(counts, 0, NN * sizeof(int), stream);
    count_kernel<<<NE / 8 / 256, 256, 0, stream>>>(dstp, counts, epos);
    scanA_kernel<<<NN / 256, 256, 0, stream>>>(counts, dinv, bsum);
    scanB_kernel<<<NN / 256, 256, 0, stream>>>(counts, bsum, rowptr);
    fill_kernel<<<NE / 8 / 256, 256, 0, stream>>>(srcp, dstp, rowptr, epos, csr_src);
    starts_kernel<<<NN / 256, 256, 0, stream>>>(batch, starts, NN);

    // layer 1: 128 -> 32
    dense_tile_kernel<128><<<NN / 128, 256, 0, stream>>>(x, W1, htmp);
    gcn_agg32v_kernel<<<NN * 8 / 256, 256, 0, stream>>>(rowptr, csr_src, htmp, dinv, b1, h1);

    // layer 2: 32 -> 32
    dense_tile_kernel<32><<<NN / 128, 256, 0, stream>>>(h1, W2, htmp);
    gcn_agg32v_kernel<<<NN * 8 / 256, 256, 0, stream>>>(rowptr, csr_src, htmp, dinv, b2, h2);

    // layer 3: 32 -> 32
    dense_tile_kernel<32><<<NN / 128, 256, 0, stream>>>(h2, W3, htmp);
    gcn_agg32v_kernel<<<NN * 8 / 256, 256, 0, stream>>>(rowptr, csr_src, htmp, dinv, b3, h3);

    // layer 4: 32 -> 1
    dense4_kernel<<<NN / 256, 256, 0, stream>>>(h3, W4, htmp);
    gcn_agg1_kernel<<<NN / 256, 256, 0, stream>>>(rowptr, csr_src, htmp, dinv, b4, h4);

    // fused sort-pool + CNN head
    pool_cnn_kernel<<<NG, 256, 0, stream>>>(h1, h2, h3, h4, starts,
                                            c1w, c1b, c2w, c2b,
                                            l1w, l1b, l2w, l2b, out);
}

// Round 4
// 347.607 us; speedup vs baseline: 2.0663x; 1.0139x over previous
//
#include <hip/hip_runtime.h>
#include <math.h>

#define NN 102400
#define NE 1638400
#define NG 2048
#define KTOP 30
#define NFEAT 97
#define NXCD 8

// ---------- XCD id (gfx950: 8 XCDs, hwreg verified on HW) ----------
__device__ __forceinline__ int get_xcd() {
    int x;
    asm volatile("s_getreg_b32 %0, hwreg(HW_REG_XCC_ID)" : "=s"(x));
    return x & 7;
}

// ---------- fused front: count (XCD-local atomics) + dense1 + starts ----------
// blocks [0,800): histogram of dst into per-XCD private counts (L2-local RMW,
//                 no cross-XCD coherence traffic); epos = (xcd<<8)|pos  (u16)
// blocks [800,1600): dense x@W1 -> htmp   (independent of CSR build)
// blocks [1600,2000): starts from sorted batch (independent)
__global__ __launch_bounds__(256) void fused_front_kernel(
    const int* __restrict__ dst, int* __restrict__ counts8,
    unsigned short* __restrict__ epos,
    const float* __restrict__ x, const float* __restrict__ W1,
    float* __restrict__ htmp,
    const int* __restrict__ batch, int* __restrict__ starts) {
    __shared__ float Wsh[128 * 32];
    int bid = blockIdx.x;
    int tid = threadIdx.x;

    if (bid < 800) {
        // ---- count role ----
        const int S = NE / 8;  // 204800
        int t = bid * 256 + tid;
        int xcd = get_xcd();
        int* cnt = counts8 + (size_t)xcd * NN;
        int d[8];
#pragma unroll
        for (int k = 0; k < 8; ++k) d[k] = dst[t + k * S];
        int p[8];
#pragma unroll
        for (int k = 0; k < 8; ++k)
            p[k] = __hip_atomic_fetch_add(&cnt[d[k]], 1, __ATOMIC_RELAXED,
                                          __HIP_MEMORY_SCOPE_WORKGROUP);
#pragma unroll
        for (int k = 0; k < 8; ++k)
            epos[t + k * S] = (unsigned short)((xcd << 8) | p[k]);
    } else if (bid < 1600) {
        // ---- dense1 role: 128 -> 32, 2 nodes x 8 outputs per thread ----
        int bidx = bid - 800;
        for (int i = tid; i < 128 * 32; i += 256) Wsh[i] = W1[i];
        __syncthreads();
        int jb = (tid >> 6) << 3;
        int q = tid & 63;
        int n0 = bidx * 128 + q;
        int n1 = n0 + 64;
        const float* x0p = x + (size_t)n0 * 128;
        const float* x1p = x + (size_t)n1 * 128;
        float acc0[8], acc1[8];
#pragma unroll
        for (int j = 0; j < 8; ++j) { acc0[j] = 0.f; acc1[j] = 0.f; }
#pragma unroll 2
        for (int k = 0; k < 128; k += 4) {
            float4 xa = *(const float4*)(x0p + k);
            float4 xb = *(const float4*)(x1p + k);
            float xs0[4] = {xa.x, xa.y, xa.z, xa.w};
            float xs1[4] = {xb.x, xb.y, xb.z, xb.w};
#pragma unroll
            for (int kk = 0; kk < 4; ++kk) {
                float4 wlo = *(const float4*)&Wsh[(k + kk) * 32 + jb];
                float4 whi = *(const float4*)&Wsh[(k + kk) * 32 + jb + 4];
                float v0 = xs0[kk], v1 = xs1[kk];
                acc0[0] += v0 * wlo.x; acc0[1] += v0 * wlo.y;
                acc0[2] += v0 * wlo.z; acc0[3] += v0 * wlo.w;
                acc0[4] += v0 * whi.x; acc0[5] += v0 * whi.y;
                acc0[6] += v0 * whi.z; acc0[7] += v0 * whi.w;
                acc1[0] += v1 * wlo.x; acc1[1] += v1 * wlo.y;
                acc1[2] += v1 * wlo.z; acc1[3] += v1 * wlo.w;
                acc1[4] += v1 * whi.x; acc1[5] += v1 * whi.y;
                acc1[6] += v1 * whi.z; acc1[7] += v1 * whi.w;
            }
        }
        float4 o0 = {acc0[0], acc0[1], acc0[2], acc0[3]};
        float4 o1 = {acc0[4], acc0[5], acc0[6], acc0[7]};
        float4 o2 = {acc1[0], acc1[1], acc1[2], acc1[3]};
        float4 o3 = {acc1[4], acc1[5], acc1[6], acc1[7]};
        *(float4*)&htmp[(size_t)n0 * 32 + jb] = o0;
        *(float4*)&htmp[(size_t)n0 * 32 + jb + 4] = o1;
        *(float4*)&htmp[(size_t)n1 * 32 + jb] = o2;
        *(float4*)&htmp[(size_t)n1 * 32 + jb + 4] = o3;
    } else {
        // ---- starts role ----
        int i = (bid - 1600) * 256 + tid;
        if (i < NN) {
            int c = batch[i];
            int p = (i == 0) ? -1 : batch[i - 1];
            for (int g = p + 1; g <= c; ++g) starts[g] = i;
            if (i == NN - 1) {
                for (int g = c + 1; g <= NG; ++g) starts[g] = NN;
            }
        }
    }
}

// ---------- scan pass A: total counts over 8 copies + dinv + block sums ----------
__global__ __launch_bounds__(256) void scanA_kernel(const int* __restrict__ counts8,
                                                    int* __restrict__ counts_tot,
                                                    float* __restrict__ dinv,
                                                    int* __restrict__ bsum) {
    __shared__ int red[256];
    int tid = threadIdx.x;
    int n = blockIdx.x * 256 + tid;
    int tot = 0;
#pragma unroll
    for (int k = 0; k < NXCD; ++k) tot += counts8[(size_t)k * NN + n];
    counts_tot[n] = tot;
    dinv[n] = rsqrtf((float)tot + 1.0f);
    red[tid] = tot;
    __syncthreads();
    for (int off = 128; off >= 1; off >>= 1) {
        if (tid < off) red[tid] += red[tid + off];
        __syncthreads();
    }
    if (tid == 0) bsum[blockIdx.x] = red[0];
}

// ---------- scan pass B: rowptr + per-(node,xcd) bases ----------
__global__ __launch_bounds__(256) void scanB_kernel(const int* __restrict__ counts_tot,
                                                    const int* __restrict__ counts8,
                                                    const int* __restrict__ bsum,
                                                    int* __restrict__ rowptr,
                                                    int* __restrict__ rowbase) {
    __shared__ int tmp[256];
    int b = blockIdx.x, tid = threadIdx.x;
    const int NB = NN / 256;  // 400
    int v = 0;
    if (tid < b) v += bsum[tid];
    if (tid + 256 < b) v += bsum[tid + 256];
    tmp[tid] = v;
    __syncthreads();
    for (int off = 128; off >= 1; off >>= 1) {
        if (tid < off) tmp[tid] += tmp[tid + off];
        __syncthreads();
    }
    int base = tmp[0];
    __syncthreads();
    int n = b * 256 + tid;
    int c = counts_tot[n];
    tmp[tid] = c;
    __syncthreads();
    for (int off = 1; off < 256; off <<= 1) {
        int u = (tid >= off) ? tmp[tid - off] : 0;
        __syncthreads();
        tmp[tid] += u;
        __syncthreads();
    }
    int rp = base + tmp[tid] - c;  // exclusive
    rowptr[n] = rp;
    int run = rp;
#pragma unroll
    for (int k = 0; k < NXCD; ++k) {
        rowbase[(size_t)n * 8 + k] = run;
        run += counts8[(size_t)k * NN + n];
    }
    if (b == NB - 1 && tid == 255) rowptr[NN] = run;
}

// ---------- fill: pure scatter, one gather per edge ----------
__global__ __launch_bounds__(256) void fill_kernel(const int* __restrict__ src,
                                                   const int* __restrict__ dst,
                                                   const int* __restrict__ rowbase,
                                                   const unsigned short* __restrict__ epos,
                                                   int* __restrict__ csr_src) {
    const int S = NE / 8;
    int t = blockIdx.x * 256 + threadIdx.x;
    int d[8], s[8], rb[8];
    unsigned short ep[8];
#pragma unroll
    for (int k = 0; k < 8; ++k) d[k] = dst[t + k * S];
#pragma unroll
    for (int k = 0; k < 8; ++k) ep[k] = epos[t + k * S];
#pragma unroll
    for (int k = 0; k < 8; ++k) s[k] = src[t + k * S];
#pragma unroll
    for (int k = 0; k < 8; ++k) rb[k] = rowbase[(size_t)d[k] * 8 + (ep[k] >> 8)];
#pragma unroll
    for (int k = 0; k < 8; ++k) csr_src[rb[k] + (ep[k] & 255)] = s[k];
}

// ---------- dense: tiled, 2 nodes x 8 outputs per thread (layers 2,3) ----------
template <int FIN>
__global__ __launch_bounds__(256) void dense_tile_kernel(const float* __restrict__ x,
                                                         const float* __restrict__ W,
                                                         float* __restrict__ out) {
    __shared__ float Wsh[FIN * 32];
    for (int i = threadIdx.x; i < FIN * 32; i += 256) Wsh[i] = W[i];
    __syncthreads();
    int jb = (threadIdx.x >> 6) << 3;
    int q = threadIdx.x & 63;
    int n0 = blockIdx.x * 128 + q;
    int n1 = n0 + 64;
    const float* x0p = x + (size_t)n0 * FIN;
    const float* x1p = x + (size_t)n1 * FIN;
    float acc0[8], acc1[8];
#pragma unroll
    for (int j = 0; j < 8; ++j) { acc0[j] = 0.f; acc1[j] = 0.f; }
#pragma unroll 2
    for (int k = 0; k < FIN; k += 4) {
        float4 xa = *(const float4*)(x0p + k);
        float4 xb = *(const float4*)(x1p + k);
        float xs0[4] = {xa.x, xa.y, xa.z, xa.w};
        float xs1[4] = {xb.x, xb.y, xb.z, xb.w};
#pragma unroll
        for (int kk = 0; kk < 4; ++kk) {
            float4 wlo = *(const float4*)&Wsh[(k + kk) * 32 + jb];
            float4 whi = *(const float4*)&Wsh[(k + kk) * 32 + jb + 4];
            float v0 = xs0[kk], v1 = xs1[kk];
            acc0[0] += v0 * wlo.x; acc0[1] += v0 * wlo.y;
            acc0[2] += v0 * wlo.z; acc0[3] += v0 * wlo.w;
            acc0[4] += v0 * whi.x; acc0[5] += v0 * whi.y;
            acc0[6] += v0 * whi.z; acc0[7] += v0 * whi.w;
            acc1[0] += v1 * wlo.x; acc1[1] += v1 * wlo.y;
            acc1[2] += v1 * wlo.z; acc1[3] += v1 * wlo.w;
            acc1[4] += v1 * whi.x; acc1[5] += v1 * whi.y;
            acc1[6] += v1 * whi.z; acc1[7] += v1 * whi.w;
        }
    }
    float4 o0 = {acc0[0], acc0[1], acc0[2], acc0[3]};
    float4 o1 = {acc0[4], acc0[5], acc0[6], acc0[7]};
    float4 o2 = {acc1[0], acc1[1], acc1[2], acc1[3]};
    float4 o3 = {acc1[4], acc1[5], acc1[6], acc1[7]};
    *(float4*)&out[(size_t)n0 * 32 + jb] = o0;
    *(float4*)&out[(size_t)n0 * 32 + jb + 4] = o1;
    *(float4*)&out[(size_t)n1 * 32 + jb] = o2;
    *(float4*)&out[(size_t)n1 * 32 + jb + 4] = o3;
}

// 32 -> 1 dense, float4 row loads
__global__ __launch_bounds__(256) void dense4_kernel(const float* __restrict__ x,
                                                     const float* __restrict__ W,
                                                     float* __restrict__ out) {
    __shared__ float Ws[32];
    if (threadIdx.x < 32) Ws[threadIdx.x] = W[threadIdx.x];
    __syncthreads();
    int n = blockIdx.x * 256 + threadIdx.x;
    if (n >= NN) return;
    const float4* xr = (const float4*)(x + (size_t)n * 32);
    float s = 0.f;
#pragma unroll
    for (int qq = 0; qq < 8; ++qq) {
        float4 v = xr[qq];
        float4 wv = *(const float4*)&Ws[qq * 4];
        s += v.x * wv.x; s += v.y * wv.y; s += v.z * wv.z; s += v.w * wv.w;
    }
    out[n] = s;
}

// ---------- fused gather-aggregate + self-term + bias + tanh ----------

__global__ __launch_bounds__(256) void gcn_agg32v_kernel(
    const int* __restrict__ rowptr, const int* __restrict__ csr_src,
    const float* __restrict__ htmp, const float* __restrict__ dinv,
    const float* __restrict__ b, float* __restrict__ hout) {
    int idx = blockIdx.x * 256 + threadIdx.x;
    int n = idx >> 3, fg = (idx & 7) << 2;
    if (n >= NN) return;
    int beg = rowptr[n], end = rowptr[n + 1];
    float di = dinv[n];
    float4 acc = {0.f, 0.f, 0.f, 0.f};
    int i = beg;
    for (; i + 7 < end; i += 8) {
        int s[8];
#pragma unroll
        for (int k = 0; k < 8; ++k) s[k] = csr_src[i + k];
        float c[8];
#pragma unroll
        for (int k = 0; k < 8; ++k) c[k] = dinv[s[k]] * di;
        float4 v[8];
#pragma unroll
        for (int k = 0; k < 8; ++k) v[k] = *(const float4*)&htmp[(size_t)s[k] * 32 + fg];
#pragma unroll
        for (int k = 0; k < 8; ++k) {
            acc.x += v[k].x * c[k]; acc.y += v[k].y * c[k];
            acc.z += v[k].z * c[k]; acc.w += v[k].w * c[k];
        }
    }
    for (; i + 3 < end; i += 4) {
        int s0 = csr_src[i], s1 = csr_src[i + 1];
        int s2 = csr_src[i + 2], s3 = csr_src[i + 3];
        float c0 = dinv[s0] * di, c1 = dinv[s1] * di;
        float c2 = dinv[s2] * di, c3 = dinv[s3] * di;
        float4 v0 = *(const float4*)&htmp[(size_t)s0 * 32 + fg];
        float4 v1 = *(const float4*)&htmp[(size_t)s1 * 32 + fg];
        float4 v2 = *(const float4*)&htmp[(size_t)s2 * 32 + fg];
        float4 v3 = *(const float4*)&htmp[(size_t)s3 * 32 + fg];
        acc.x += v0.x * c0; acc.y += v0.y * c0; acc.z += v0.z * c0; acc.w += v0.w * c0;
        acc.x += v1.x * c1; acc.y += v1.y * c1; acc.z += v1.z * c1; acc.w += v1.w * c1;
        acc.x += v2.x * c2; acc.y += v2.y * c2; acc.z += v2.z * c2; acc.w += v2.w * c2;
        acc.x += v3.x * c3; acc.y += v3.y * c3; acc.z += v3.z * c3; acc.w += v3.w * c3;
    }
    for (; i < end; ++i) {
        int s = csr_src[i];
        float c = dinv[s] * di;
        float4 v = *(const float4*)&htmp[(size_t)s * 32 + fg];
        acc.x += v.x * c; acc.y += v.y * c; acc.z += v.z * c; acc.w += v.w * c;
    }
    float dd = di * di;
    float4 hs = *(const float4*)&htmp[(size_t)n * 32 + fg];
    float4 bb = *(const float4*)&b[fg];
    float4 o;
    o.x = tanhf(acc.x + hs.x * dd + bb.x);
    o.y = tanhf(acc.y + hs.y * dd + bb.y);
    o.z = tanhf(acc.z + hs.z * dd + bb.z);
    o.w = tanhf(acc.w + hs.w * dd + bb.w);
    *(float4*)&hout[(size_t)n * 32 + fg] = o;
}

__global__ __launch_bounds__(256) void gcn_agg1_kernel(
    const int* __restrict__ rowptr, const int* __restrict__ csr_src,
    const float* __restrict__ htmp, const float* __restrict__ dinv,
    const float* __restrict__ b, float* __restrict__ hout) {
    int n = blockIdx.x * blockDim.x + threadIdx.x;
    if (n >= NN) return;
    int beg = rowptr[n], end = rowptr[n + 1];
    float di = dinv[n];
    float acc = 0.f;
    int i = beg;
    for (; i + 7 < end; i += 8) {
        int s[8];
#pragma unroll
        for (int k = 0; k < 8; ++k) s[k] = csr_src[i + k];
        float c[8], v[8];
#pragma unroll
        for (int k = 0; k < 8; ++k) c[k] = dinv[s[k]] * di;
#pragma unroll
        for (int k = 0; k < 8; ++k) v[k] = htmp[s[k]];
#pragma unroll
        for (int k = 0; k < 8; ++k) acc += v[k] * c[k];
    }
    for (; i + 3 < end; i += 4) {
        int s0 = csr_src[i], s1 = csr_src[i + 1];
        int s2 = csr_src[i + 2], s3 = csr_src[i + 3];
        float c0 = dinv[s0] * di, c1 = dinv[s1] * di;
        float c2 = dinv[s2] * di, c3 = dinv[s3] * di;
        acc += htmp[s0] * c0;
        acc += htmp[s1] * c1;
        acc += htmp[s2] * c2;
        acc += htmp[s3] * c3;
    }
    for (; i < end; ++i) {
        int s = csr_src[i];
        acc += htmp[s] * (dinv[s] * di);
    }
    hout[n] = tanhf(acc + htmp[n] * di * di + b[0]);
}

// ---------- sort-pool + CNN head ----------

#define PSTR 100

__global__ __launch_bounds__(256) void pool_cnn_kernel(
    const float* __restrict__ h1, const float* __restrict__ h2,
    const float* __restrict__ h3, const float* __restrict__ h4,
    const int* __restrict__ starts,
    const float* __restrict__ c1w, const float* __restrict__ c1b,
    const float* __restrict__ c2w, const float* __restrict__ c2b,
    const float* __restrict__ l1w, const float* __restrict__ l1b,
    const float* __restrict__ l2w, const float* __restrict__ l2b,
    float* __restrict__ out) {
    __shared__ float P[KTOP][PSTR];
    __shared__ float CW[16 * PSTR];
    __shared__ float KY[480];
    float* keys = KY;
    float* y2 = &P[0][0];
    float* y3 = &P[0][0] + 240;
    float* z  = &P[0][0] + 592;
    int g = blockIdx.x;
    int tid = threadIdx.x;

    int start = starts[g];
    int end = starts[g + 1];
    int cnt = end - start;

    for (int i = tid; i < KTOP * PSTR; i += 256) (&P[0][0])[i] = 0.f;
    for (int i = tid; i < 16 * 97; i += 256) {
        int c = i / 97, f = i % 97;
        CW[c * PSTR + f] = c1w[i];
    }
    bool fits = (cnt <= 256);
    if (fits) {
        for (int i = tid; i < cnt; i += 256) keys[i] = h4[start + i];
    }
    __syncthreads();

    for (int i = tid; i < cnt; i += 256) {
        float key = fits ? keys[i] : h4[start + i];
        int rank = 0;
        if (fits) {
            for (int j = 0; j < cnt; ++j) {
                float kj = keys[j];
                rank += (kj > key) || (kj == key && j < i);
            }
        } else {
            for (int j = 0; j < cnt; ++j) {
                float kj = h4[start + j];
                rank += (kj > key) || (kj == key && j < i);
            }
        }
        if (rank < KTOP) {
            int node = start + i;
            const float4* r1 = (const float4*)(h1 + (size_t)node * 32);
            const float4* r2 = (const float4*)(h2 + (size_t)node * 32);
            const float4* r3 = (const float4*)(h3 + (size_t)node * 32);
#pragma unroll
            for (int q = 0; q < 8; ++q) *(float4*)&P[rank][4 * q] = r1[q];
#pragma unroll
            for (int q = 0; q < 8; ++q) *(float4*)&P[rank][32 + 4 * q] = r2[q];
#pragma unroll
            for (int q = 0; q < 8; ++q) *(float4*)&P[rank][64 + 4 * q] = r3[q];
            P[rank][96] = key;
        }
    }
    __syncthreads();

    for (int o = tid; o < 16 * KTOP; o += 256) {
        int c = o / KTOP, t = o % KTOP;
        float s = c1b[c];
        const float* Pr = &P[t][0];
        const float* Wr = &CW[c * PSTR];
#pragma unroll
        for (int f4 = 0; f4 < 24; ++f4) {
            float4 pv = *(const float4*)(Pr + 4 * f4);
            float4 wv = *(const float4*)(Wr + 4 * f4);
            s += wv.x * pv.x; s += wv.y * pv.y; s += wv.z * pv.z; s += wv.w * pv.w;
        }
        s += Wr[96] * Pr[96];
        KY[c * KTOP + t] = fmaxf(s, 0.f);
    }
    __syncthreads();

    for (int o = tid; o < 16 * 15; o += 256) {
        int c = o / 15, t = o % 15;
        y2[o] = fmaxf(KY[c * KTOP + 2 * t], KY[c * KTOP + 2 * t + 1]);
    }
    __syncthreads();

    for (int o = tid; o < 32 * 11; o += 256) {
        int c = o / 11, t = o % 11;
        float s = c2b[c];
#pragma unroll
        for (int i = 0; i < 16; ++i)
#pragma unroll
            for (int j = 0; j < 5; ++j)
                s += c2w[(c * 16 + i) * 5 + j] * y2[i * 15 + t + j];
        y3[o] = fmaxf(s, 0.f);
    }
    __syncthreads();

    for (int o = tid; o < 128; o += 256) {
        float s = l1b[o];
#pragma unroll 16
        for (int i = 0; i < 352; ++i) s += y3[i] * l1w[i * 128 + o];
        z[o] = fmaxf(s, 0.f);
    }
    __syncthreads();

    if (tid == 0) {
        float s = l2b[0];
#pragma unroll 4
        for (int i = 0; i < 128; ++i) s += z[i] * l2w[i];
        out[g] = 1.f / (1.f + expf(-s));
    }
}

extern "C" void kernel_launch(void* const* d_in, const int* in_sizes, int n_in,
                              void* d_out, int out_size, void* d_ws, size_t ws_size,
                              hipStream_t stream) {
    const float* x   = (const float*)d_in[0];
    const int* ei    = (const int*)d_in[1];
    const int* batch = (const int*)d_in[2];
    const float* W1  = (const float*)d_in[3];
    const float* b1  = (const float*)d_in[4];
    const float* W2  = (const float*)d_in[5];
    const float* b2  = (const float*)d_in[6];
    const float* W3  = (const float*)d_in[7];
    const float* b3  = (const float*)d_in[8];
    const float* W4  = (const float*)d_in[9];
    const float* b4  = (const float*)d_in[10];
    const float* c1w = (const float*)d_in[11];
    const float* c1b = (const float*)d_in[12];
    const float* c2w = (const float*)d_in[13];
    const float* c2b = (const float*)d_in[14];
    const float* l1w = (const float*)d_in[15];
    const float* l1b = (const float*)d_in[16];
    const float* l2w = (const float*)d_in[17];
    const float* l2b = (const float*)d_in[18];
    float* out = (float*)d_out;

    const int* srcp = ei;
    const int* dstp = ei + NE;

    // workspace layout
    char* w = (char*)d_ws;
    float* dinv      = (float*)w;               w += sizeof(float) * NN;
    float* htmp      = (float*)w;               w += sizeof(float) * NN * 32;
    float* h1        = (float*)w;               w += sizeof(float) * NN * 32;
    float* h2        = (float*)w;               w += sizeof(float) * NN * 32;
    float* h3        = (float*)w;               w += sizeof(float) * NN * 32;
    float* h4        = (float*)w;               w += sizeof(float) * NN;
    int*   counts8   = (int*)w;                 w += sizeof(int) * NN * NXCD;
    int*   counts_tot= (int*)w;                 w += sizeof(int) * NN;
    int*   rowptr    = (int*)w;                 w += sizeof(int) * (NN + 1);
    int*   rowbase   = (int*)w;                 w += sizeof(int) * NN * NXCD;
    unsigned short* epos = (unsigned short*)w;  w += sizeof(unsigned short) * NE;
    int*   csr_src   = (int*)w;                 w += sizeof(int) * NE;
    int*   bsum      = (int*)w;                 w += sizeof(int) * (NN / 256);
    int*   starts    = (int*)w;                 w += sizeof(int) * (NG + 1);

    hipMemsetAsync(counts8, 0, (size_t)NN * NXCD * sizeof(int), stream);

    // fused front: count (XCD-local) + dense1 + starts, all concurrent
    fused_front_kernel<<<2000, 256, 0, stream>>>(dstp, counts8, epos, x, W1, htmp,
                                                 batch, starts);
    scanA_kernel<<<NN / 256, 256, 0, stream>>>(counts8, counts_tot, dinv, bsum);
    scanB_kernel<<<NN / 256, 256, 0, stream>>>(counts_tot, counts8, bsum, rowptr, rowbase);
    fill_kernel<<<NE / 8 / 256, 256, 0, stream>>>(srcp, dstp, rowbase, epos, csr_src);

    // layer 1 aggregate (dense1 already done in fused front)
    gcn_agg32v_kernel<<<NN * 8 / 256, 256, 0, stream>>>(rowptr, csr_src, htmp, dinv, b1, h1);

    // layer 2: 32 -> 32
    dense_tile_kernel<32><<<NN / 128, 256, 0, stream>>>(h1, W2, htmp);
    gcn_agg32v_kernel<<<NN * 8 / 256, 256, 0, stream>>>(rowptr, csr_src, htmp, dinv, b2, h2);

    // layer 3: 32 -> 32
    dense_tile_kernel<32><<<NN / 128, 256, 0, stream>>>(h2, W3, htmp);
    gcn_agg32v_kernel<<<NN * 8 / 256, 256, 0, stream>>>(rowptr, csr_src, htmp, dinv, b3, h3);

    // layer 4: 32 -> 1
    dense4_kernel<<<NN / 256, 256, 0, stream>>>(h3, W4, htmp);
    gcn_agg1_kernel<<<NN / 256, 256, 0, stream>>>(rowptr, csr_src, htmp, dinv, b4, h4);

    // fused sort-pool + CNN head
    pool_cnn_kernel<<<NG, 256, 0, stream>>>(h1, h2, h3, h4, starts,
                                            c1w, c1b, c2w, c2b,
                                            l1w, l1b, l2w, l2b, out);
}

// Round 5
// 277.067 us; speedup vs baseline: 2.5924x; 1.2546x over previous
//
#include <hip/hip_runtime.h>
#include <math.h>

#define NN 102400
#define NE 1638400
#define NG 2048
#define KTOP 30
#define NBUCK 400   // coarse buckets of 256 nodes (dst >> 8)
#define EPB 4096    // edges per pass-1 block
#define NB1 400     // NE / EPB

// ---------- fused front: coarse histogram + dense1 + starts ----------
// blocks [0,400):      H1 — per-block coarse histogram of dst (LDS atomics only)
// blocks [400,1200):   dense x@W1 -> htmp
// blocks [1200,1600):  starts from sorted batch
__global__ __launch_bounds__(256) void fused_front_kernel(
    const int* __restrict__ dst, int* __restrict__ hist1,
    const float* __restrict__ x, const float* __restrict__ W1,
    float* __restrict__ htmp,
    const int* __restrict__ batch, int* __restrict__ starts) {
    __shared__ float Wsh[128 * 32];
    __shared__ int hsh[NBUCK];
    int bid = blockIdx.x;
    int tid = threadIdx.x;

    if (bid < NB1) {
        // ---- H1: coarse histogram ----
        for (int q = tid; q < NBUCK; q += 256) hsh[q] = 0;
        __syncthreads();
        int base = bid * EPB;
#pragma unroll 4
        for (int i = tid; i < EPB; i += 256) {
            int d = dst[base + i];
            atomicAdd(&hsh[d >> 8], 1);
        }
        __syncthreads();
        for (int q = tid; q < NBUCK; q += 256) hist1[q * NB1 + bid] = hsh[q];
    } else if (bid < NB1 + 800) {
        // ---- dense1: 128 -> 32, 2 nodes x 8 outputs per thread ----
        int bidx = bid - NB1;
        for (int i = tid; i < 128 * 32; i += 256) Wsh[i] = W1[i];
        __syncthreads();
        int jb = (tid >> 6) << 3;
        int q = tid & 63;
        int n0 = bidx * 128 + q;
        int n1 = n0 + 64;
        const float* x0p = x + (size_t)n0 * 128;
        const float* x1p = x + (size_t)n1 * 128;
        float acc0[8], acc1[8];
#pragma unroll
        for (int j = 0; j < 8; ++j) { acc0[j] = 0.f; acc1[j] = 0.f; }
#pragma unroll 2
        for (int k = 0; k < 128; k += 4) {
            float4 xa = *(const float4*)(x0p + k);
            float4 xb = *(const float4*)(x1p + k);
            float xs0[4] = {xa.x, xa.y, xa.z, xa.w};
            float xs1[4] = {xb.x, xb.y, xb.z, xb.w};
#pragma unroll
            for (int kk = 0; kk < 4; ++kk) {
                float4 wlo = *(const float4*)&Wsh[(k + kk) * 32 + jb];
                float4 whi = *(const float4*)&Wsh[(k + kk) * 32 + jb + 4];
                float v0 = xs0[kk], v1 = xs1[kk];
                acc0[0] += v0 * wlo.x; acc0[1] += v0 * wlo.y;
                acc0[2] += v0 * wlo.z; acc0[3] += v0 * wlo.w;
                acc0[4] += v0 * whi.x; acc0[5] += v0 * whi.y;
                acc0[6] += v0 * whi.z; acc0[7] += v0 * whi.w;
                acc1[0] += v1 * wlo.x; acc1[1] += v1 * wlo.y;
                acc1[2] += v1 * wlo.z; acc1[3] += v1 * wlo.w;
                acc1[4] += v1 * whi.x; acc1[5] += v1 * whi.y;
                acc1[6] += v1 * whi.z; acc1[7] += v1 * whi.w;
            }
        }
        float4 o0 = {acc0[0], acc0[1], acc0[2], acc0[3]};
        float4 o1 = {acc0[4], acc0[5], acc0[6], acc0[7]};
        float4 o2 = {acc1[0], acc1[1], acc1[2], acc1[3]};
        float4 o3 = {acc1[4], acc1[5], acc1[6], acc1[7]};
        *(float4*)&htmp[(size_t)n0 * 32 + jb] = o0;
        *(float4*)&htmp[(size_t)n0 * 32 + jb + 4] = o1;
        *(float4*)&htmp[(size_t)n1 * 32 + jb] = o2;
        *(float4*)&htmp[(size_t)n1 * 32 + jb + 4] = o3;
    } else {
        // ---- starts ----
        int i = (bid - NB1 - 800) * 256 + tid;
        if (i < NN) {
            int c = batch[i];
            int p = (i == 0) ? -1 : batch[i - 1];
            for (int g = p + 1; g <= c; ++g) starts[g] = i;
            if (i == NN - 1) {
                for (int g = c + 1; g <= NG; ++g) starts[g] = NN;
            }
        }
    }
}

// ---------- S1a: per-bucket scan over blocks -> intra-bucket block offsets + totals ----------
__global__ __launch_bounds__(256) void s1a_kernel(const int* __restrict__ hist1,
                                                  int* __restrict__ offs,
                                                  int* __restrict__ totals) {
    __shared__ int A[512], B[512];
    int q = blockIdx.x, tid = threadIdx.x;
    int i0 = tid, i1 = tid + 256;
    int v0 = (i0 < NB1) ? hist1[q * NB1 + i0] : 0;
    int v1 = (i1 < NB1) ? hist1[q * NB1 + i1] : 0;
    A[i0] = v0; A[i1] = v1;
    __syncthreads();
    int* cur = A; int* nxt = B;
    for (int off = 1; off < 512; off <<= 1) {
        nxt[i0] = cur[i0] + ((i0 >= off) ? cur[i0 - off] : 0);
        nxt[i1] = cur[i1] + cur[i1 - off];
        __syncthreads();
        int* t = cur; cur = nxt; nxt = t;
    }
    if (i0 < NB1) offs[q * NB1 + i0] = cur[i0] - v0;
    if (i1 < NB1) offs[q * NB1 + i1] = cur[i1] - v1;
    if (tid == 0) totals[q] = cur[511];
}

// ---------- S1b: scan bucket totals -> bucketStart ----------
__global__ __launch_bounds__(256) void s1b_kernel(const int* __restrict__ totals,
                                                  int* __restrict__ bucketStart,
                                                  int* __restrict__ rowptr) {
    __shared__ int A[512], B[512];
    int tid = threadIdx.x;
    int i0 = tid, i1 = tid + 256;
    int v0 = (i0 < NBUCK) ? totals[i0] : 0;
    int v1 = (i1 < NBUCK) ? totals[i1] : 0;
    A[i0] = v0; A[i1] = v1;
    __syncthreads();
    int* cur = A; int* nxt = B;
    for (int off = 1; off < 512; off <<= 1) {
        nxt[i0] = cur[i0] + ((i0 >= off) ? cur[i0 - off] : 0);
        nxt[i1] = cur[i1] + cur[i1 - off];
        __syncthreads();
        int* t = cur; cur = nxt; nxt = t;
    }
    if (i0 < NBUCK) bucketStart[i0] = cur[i0] - v0;
    if (i1 < NBUCK) bucketStart[i1] = cur[i1] - v1;
    if (tid == 0) { bucketStart[NBUCK] = cur[511]; rowptr[NN] = cur[511]; }
}

// ---------- P1: scatter edges into coarse buckets (LDS-atomic slot assignment) ----------
// packed u32 = (dst & 255) << 24 | src   (src < 2^17)
__global__ __launch_bounds__(256) void p1_kernel(const int* __restrict__ src,
                                                 const int* __restrict__ dst,
                                                 const int* __restrict__ offs,
                                                 const int* __restrict__ bucketStart,
                                                 unsigned int* __restrict__ ebuf) {
    __shared__ int myoff[NBUCK];
    int b = blockIdx.x, tid = threadIdx.x;
    for (int q = tid; q < NBUCK; q += 256)
        myoff[q] = bucketStart[q] + offs[q * NB1 + b];
    __syncthreads();
    int base = b * EPB;
#pragma unroll 4
    for (int i = tid; i < EPB; i += 256) {
        int d = dst[base + i];
        int s = src[base + i];
        int pos = atomicAdd(&myoff[d >> 8], 1);
        ebuf[pos] = ((unsigned int)(d & 255) << 24) | (unsigned int)s;
    }
}

// ---------- P2: per-bucket fine counting sort -> csr_src + rowptr + dinv ----------
__global__ __launch_bounds__(256) void p2_kernel(const unsigned int* __restrict__ ebuf,
                                                 const int* __restrict__ bucketStart,
                                                 int* __restrict__ csr_src,
                                                 int* __restrict__ rowptr,
                                                 float* __restrict__ dinv) {
    __shared__ int fcnt[256];
    __shared__ int tmp[256];
    __shared__ int foff[256];
    int q = blockIdx.x, tid = threadIdx.x;
    int base = bucketStart[q];
    int ecnt = bucketStart[q + 1] - base;
    fcnt[tid] = 0;
    __syncthreads();
    for (int i = tid; i < ecnt; i += 256) {
        unsigned int e = ebuf[base + i];
        atomicAdd(&fcnt[e >> 24], 1);
    }
    __syncthreads();
    int c = fcnt[tid];
    int n = q * 256 + tid;
    dinv[n] = rsqrtf((float)c + 1.0f);
    // inclusive scan of fcnt
    tmp[tid] = c;
    __syncthreads();
    for (int off = 1; off < 256; off <<= 1) {
        int u = (tid >= off) ? tmp[tid - off] : 0;
        __syncthreads();
        tmp[tid] += u;
        __syncthreads();
    }
    int excl = base + tmp[tid] - c;
    rowptr[n] = excl;
    foff[tid] = excl;
    __syncthreads();
    for (int i = tid; i < ecnt; i += 256) {
        unsigned int e = ebuf[base + i];
        int pos = atomicAdd(&foff[e >> 24], 1);
        csr_src[pos] = (int)(e & 0xFFFFFF);
    }
}

// ---------- dense: tiled, 2 nodes x 8 outputs per thread (layers 2,3) ----------
template <int FIN>
__global__ __launch_bounds__(256) void dense_tile_kernel(const float* __restrict__ x,
                                                         const float* __restrict__ W,
                                                         float* __restrict__ out) {
    __shared__ float Wsh[FIN * 32];
    for (int i = threadIdx.x; i < FIN * 32; i += 256) Wsh[i] = W[i];
    __syncthreads();
    int jb = (threadIdx.x >> 6) << 3;
    int q = threadIdx.x & 63;
    int n0 = blockIdx.x * 128 + q;
    int n1 = n0 + 64;
    const float* x0p = x + (size_t)n0 * FIN;
    const float* x1p = x + (size_t)n1 * FIN;
    float acc0[8], acc1[8];
#pragma unroll
    for (int j = 0; j < 8; ++j) { acc0[j] = 0.f; acc1[j] = 0.f; }
#pragma unroll 2
    for (int k = 0; k < FIN; k += 4) {
        float4 xa = *(const float4*)(x0p + k);
        float4 xb = *(const float4*)(x1p + k);
        float xs0[4] = {xa.x, xa.y, xa.z, xa.w};
        float xs1[4] = {xb.x, xb.y, xb.z, xb.w};
#pragma unroll
        for (int kk = 0; kk < 4; ++kk) {
            float4 wlo = *(const float4*)&Wsh[(k + kk) * 32 + jb];
            float4 whi = *(const float4*)&Wsh[(k + kk) * 32 + jb + 4];
            float v0 = xs0[kk], v1 = xs1[kk];
            acc0[0] += v0 * wlo.x; acc0[1] += v0 * wlo.y;
            acc0[2] += v0 * wlo.z; acc0[3] += v0 * wlo.w;
            acc0[4] += v0 * whi.x; acc0[5] += v0 * whi.y;
            acc0[6] += v0 * whi.z; acc0[7] += v0 * whi.w;
            acc1[0] += v1 * wlo.x; acc1[1] += v1 * wlo.y;
            acc1[2] += v1 * wlo.z; acc1[3] += v1 * wlo.w;
            acc1[4] += v1 * whi.x; acc1[5] += v1 * whi.y;
            acc1[6] += v1 * whi.z; acc1[7] += v1 * whi.w;
        }
    }
    float4 o0 = {acc0[0], acc0[1], acc0[2], acc0[3]};
    float4 o1 = {acc0[4], acc0[5], acc0[6], acc0[7]};
    float4 o2 = {acc1[0], acc1[1], acc1[2], acc1[3]};
    float4 o3 = {acc1[4], acc1[5], acc1[6], acc1[7]};
    *(float4*)&out[(size_t)n0 * 32 + jb] = o0;
    *(float4*)&out[(size_t)n0 * 32 + jb + 4] = o1;
    *(float4*)&out[(size_t)n1 * 32 + jb] = o2;
    *(float4*)&out[(size_t)n1 * 32 + jb + 4] = o3;
}

// 32 -> 1 dense, float4 row loads
__global__ __launch_bounds__(256) void dense4_kernel(const float* __restrict__ x,
                                                     const float* __restrict__ W,
                                                     float* __restrict__ out) {
    __shared__ float Ws[32];
    if (threadIdx.x < 32) Ws[threadIdx.x] = W[threadIdx.x];
    __syncthreads();
    int n = blockIdx.x * 256 + threadIdx.x;
    if (n >= NN) return;
    const float4* xr = (const float4*)(x + (size_t)n * 32);
    float s = 0.f;
#pragma unroll
    for (int qq = 0; qq < 8; ++qq) {
        float4 v = xr[qq];
        float4 wv = *(const float4*)&Ws[qq * 4];
        s += v.x * wv.x; s += v.y * wv.y; s += v.z * wv.z; s += v.w * wv.w;
    }
    out[n] = s;
}

// ---------- fused gather-aggregate + self-term + bias + tanh ----------

__global__ __launch_bounds__(256) void gcn_agg32v_kernel(
    const int* __restrict__ rowptr, const int* __restrict__ csr_src,
    const float* __restrict__ htmp, const float* __restrict__ dinv,
    const float* __restrict__ b, float* __restrict__ hout) {
    int idx = blockIdx.x * 256 + threadIdx.x;
    int n = idx >> 3, fg = (idx & 7) << 2;
    if (n >= NN) return;
    int beg = rowptr[n], end = rowptr[n + 1];
    float di = dinv[n];
    float4 acc = {0.f, 0.f, 0.f, 0.f};
    int i = beg;
    for (; i + 7 < end; i += 8) {
        int s[8];
#pragma unroll
        for (int k = 0; k < 8; ++k) s[k] = csr_src[i + k];
        float c[8];
#pragma unroll
        for (int k = 0; k < 8; ++k) c[k] = dinv[s[k]] * di;
        float4 v[8];
#pragma unroll
        for (int k = 0; k < 8; ++k) v[k] = *(const float4*)&htmp[(size_t)s[k] * 32 + fg];
#pragma unroll
        for (int k = 0; k < 8; ++k) {
            acc.x += v[k].x * c[k]; acc.y += v[k].y * c[k];
            acc.z += v[k].z * c[k]; acc.w += v[k].w * c[k];
        }
    }
    for (; i + 3 < end; i += 4) {
        int s0 = csr_src[i], s1 = csr_src[i + 1];
        int s2 = csr_src[i + 2], s3 = csr_src[i + 3];
        float c0 = dinv[s0] * di, c1 = dinv[s1] * di;
        float c2 = dinv[s2] * di, c3 = dinv[s3] * di;
        float4 v0 = *(const float4*)&htmp[(size_t)s0 * 32 + fg];
        float4 v1 = *(const float4*)&htmp[(size_t)s1 * 32 + fg];
        float4 v2 = *(const float4*)&htmp[(size_t)s2 * 32 + fg];
        float4 v3 = *(const float4*)&htmp[(size_t)s3 * 32 + fg];
        acc.x += v0.x * c0; acc.y += v0.y * c0; acc.z += v0.z * c0; acc.w += v0.w * c0;
        acc.x += v1.x * c1; acc.y += v1.y * c1; acc.z += v1.z * c1; acc.w += v1.w * c1;
        acc.x += v2.x * c2; acc.y += v2.y * c2; acc.z += v2.z * c2; acc.w += v2.w * c2;
        acc.x += v3.x * c3; acc.y += v3.y * c3; acc.z += v3.z * c3; acc.w += v3.w * c3;
    }
    for (; i < end; ++i) {
        int s = csr_src[i];
        float c = dinv[s] * di;
        float4 v = *(const float4*)&htmp[(size_t)s * 32 + fg];
        acc.x += v.x * c; acc.y += v.y * c; acc.z += v.z * c; acc.w += v.w * c;
    }
    float dd = di * di;
    float4 hs = *(const float4*)&htmp[(size_t)n * 32 + fg];
    float4 bb = *(const float4*)&b[fg];
    float4 o;
    o.x = tanhf(acc.x + hs.x * dd + bb.x);
    o.y = tanhf(acc.y + hs.y * dd + bb.y);
    o.z = tanhf(acc.z + hs.z * dd + bb.z);
    o.w = tanhf(acc.w + hs.w * dd + bb.w);
    *(float4*)&hout[(size_t)n * 32 + fg] = o;
}

__global__ __launch_bounds__(256) void gcn_agg1_kernel(
    const int* __restrict__ rowptr, const int* __restrict__ csr_src,
    const float* __restrict__ htmp, const float* __restrict__ dinv,
    const float* __restrict__ b, float* __restrict__ hout) {
    int n = blockIdx.x * blockDim.x + threadIdx.x;
    if (n >= NN) return;
    int beg = rowptr[n], end = rowptr[n + 1];
    float di = dinv[n];
    float acc = 0.f;
    int i = beg;
    for (; i + 7 < end; i += 8) {
        int s[8];
#pragma unroll
        for (int k = 0; k < 8; ++k) s[k] = csr_src[i + k];
        float c[8], v[8];
#pragma unroll
        for (int k = 0; k < 8; ++k) c[k] = dinv[s[k]] * di;
#pragma unroll
        for (int k = 0; k < 8; ++k) v[k] = htmp[s[k]];
#pragma unroll
        for (int k = 0; k < 8; ++k) acc += v[k] * c[k];
    }
    for (; i + 3 < end; i += 4) {
        int s0 = csr_src[i], s1 = csr_src[i + 1];
        int s2 = csr_src[i + 2], s3 = csr_src[i + 3];
        float c0 = dinv[s0] * di, c1 = dinv[s1] * di;
        float c2 = dinv[s2] * di, c3 = dinv[s3] * di;
        acc += htmp[s0] * c0;
        acc += htmp[s1] * c1;
        acc += htmp[s2] * c2;
        acc += htmp[s3] * c3;
    }
    for (; i < end; ++i) {
        int s = csr_src[i];
        acc += htmp[s] * (dinv[s] * di);
    }
    hout[n] = tanhf(acc + htmp[n] * di * di + b[0]);
}

// ---------- sort-pool + CNN head ----------

#define PSTR 100

__global__ __launch_bounds__(256) void pool_cnn_kernel(
    const float* __restrict__ h1, const float* __restrict__ h2,
    const float* __restrict__ h3, const float* __restrict__ h4,
    const int* __restrict__ starts,
    const float* __restrict__ c1w, const float* __restrict__ c1b,
    const float* __restrict__ c2w, const float* __restrict__ c2b,
    const float* __restrict__ l1w, const float* __restrict__ l1b,
    const float* __restrict__ l2w, const float* __restrict__ l2b,
    float* __restrict__ out) {
    __shared__ float P[KTOP][PSTR];
    __shared__ float CW[16 * PSTR];
    __shared__ float KY[480];
    float* keys = KY;
    float* y2 = &P[0][0];
    float* y3 = &P[0][0] + 240;
    float* z  = &P[0][0] + 592;
    int g = blockIdx.x;
    int tid = threadIdx.x;

    int start = starts[g];
    int end = starts[g + 1];
    int cnt = end - start;

    for (int i = tid; i < KTOP * PSTR; i += 256) (&P[0][0])[i] = 0.f;
    for (int i = tid; i < 16 * 97; i += 256) {
        int c = i / 97, f = i % 97;
        CW[c * PSTR + f] = c1w[i];
    }
    bool fits = (cnt <= 256);
    if (fits) {
        for (int i = tid; i < cnt; i += 256) keys[i] = h4[start + i];
    }
    __syncthreads();

    for (int i = tid; i < cnt; i += 256) {
        float key = fits ? keys[i] : h4[start + i];
        int rank = 0;
        if (fits) {
            for (int j = 0; j < cnt; ++j) {
                float kj = keys[j];
                rank += (kj > key) || (kj == key && j < i);
            }
        } else {
            for (int j = 0; j < cnt; ++j) {
                float kj = h4[start + j];
                rank += (kj > key) || (kj == key && j < i);
            }
        }
        if (rank < KTOP) {
            int node = start + i;
            const float4* r1 = (const float4*)(h1 + (size_t)node * 32);
            const float4* r2 = (const float4*)(h2 + (size_t)node * 32);
            const float4* r3 = (const float4*)(h3 + (size_t)node * 32);
#pragma unroll
            for (int q = 0; q < 8; ++q) *(float4*)&P[rank][4 * q] = r1[q];
#pragma unroll
            for (int q = 0; q < 8; ++q) *(float4*)&P[rank][32 + 4 * q] = r2[q];
#pragma unroll
            for (int q = 0; q < 8; ++q) *(float4*)&P[rank][64 + 4 * q] = r3[q];
            P[rank][96] = key;
        }
    }
    __syncthreads();

    for (int o = tid; o < 16 * KTOP; o += 256) {
        int c = o / KTOP, t = o % KTOP;
        float s = c1b[c];
        const float* Pr = &P[t][0];
        const float* Wr = &CW[c * PSTR];
#pragma unroll
        for (int f4 = 0; f4 < 24; ++f4) {
            float4 pv = *(const float4*)(Pr + 4 * f4);
            float4 wv = *(const float4*)(Wr + 4 * f4);
            s += wv.x * pv.x; s += wv.y * pv.y; s += wv.z * pv.z; s += wv.w * pv.w;
        }
        s += Wr[96] * Pr[96];
        KY[c * KTOP + t] = fmaxf(s, 0.f);
    }
    __syncthreads();

    for (int o = tid; o < 16 * 15; o += 256) {
        int c = o / 15, t = o % 15;
        y2[o] = fmaxf(KY[c * KTOP + 2 * t], KY[c * KTOP + 2 * t + 1]);
    }
    __syncthreads();

    for (int o = tid; o < 32 * 11; o += 256) {
        int c = o / 11, t = o % 11;
        float s = c2b[c];
#pragma unroll
        for (int i = 0; i < 16; ++i)
#pragma unroll
            for (int j = 0; j < 5; ++j)
                s += c2w[(c * 16 + i) * 5 + j] * y2[i * 15 + t + j];
        y3[o] = fmaxf(s, 0.f);
    }
    __syncthreads();

    for (int o = tid; o < 128; o += 256) {
        float s = l1b[o];
#pragma unroll 16
        for (int i = 0; i < 352; ++i) s += y3[i] * l1w[i * 128 + o];
        z[o] = fmaxf(s, 0.f);
    }
    __syncthreads();

    if (tid == 0) {
        float s = l2b[0];
#pragma unroll 4
        for (int i = 0; i < 128; ++i) s += z[i] * l2w[i];
        out[g] = 1.f / (1.f + expf(-s));
    }
}

extern "C" void kernel_launch(void* const* d_in, const int* in_sizes, int n_in,
                              void* d_out, int out_size, void* d_ws, size_t ws_size,
                              hipStream_t stream) {
    const float* x   = (const float*)d_in[0];
    const int* ei    = (const int*)d_in[1];
    const int* batch = (const int*)d_in[2];
    const float* W1  = (const float*)d_in[3];
    const float* b1  = (const float*)d_in[4];
    const float* W2  = (const float*)d_in[5];
    const float* b2  = (const float*)d_in[6];
    const float* W3  = (const float*)d_in[7];
    const float* b3  = (const float*)d_in[8];
    const float* W4  = (const float*)d_in[9];
    const float* b4  = (const float*)d_in[10];
    const float* c1w = (const float*)d_in[11];
    const float* c1b = (const float*)d_in[12];
    const float* c2w = (const float*)d_in[13];
    const float* c2b = (const float*)d_in[14];
    const float* l1w = (const float*)d_in[15];
    const float* l1b = (const float*)d_in[16];
    const float* l2w = (const float*)d_in[17];
    const float* l2b = (const float*)d_in[18];
    float* out = (float*)d_out;

    const int* srcp = ei;
    const int* dstp = ei + NE;

    // workspace layout
    char* w = (char*)d_ws;
    float* dinv      = (float*)w;               w += sizeof(float) * NN;
    float* htmp      = (float*)w;               w += sizeof(float) * NN * 32;
    float* h1        = (float*)w;               w += sizeof(float) * NN * 32;
    float* h2        = (float*)w;               w += sizeof(float) * NN * 32;  // ebuf aliases here
    float* h3        = (float*)w;               w += sizeof(float) * NN * 32;
    float* h4        = (float*)w;               w += sizeof(float) * NN;
    int*   rowptr    = (int*)w;                 w += sizeof(int) * (NN + 1);
    int*   hist1     = (int*)w;                 w += sizeof(int) * NBUCK * NB1;
    int*   offs      = (int*)w;                 w += sizeof(int) * NBUCK * NB1;
    int*   totals    = (int*)w;                 w += sizeof(int) * NBUCK;
    int*   bucketStart = (int*)w;               w += sizeof(int) * (NBUCK + 1);
    int*   csr_src   = (int*)w;                 w += sizeof(int) * NE;
    int*   starts    = (int*)w;                 w += sizeof(int) * (NG + 1);

    // ebuf (NE u32 = 6.55 MB) aliases h2 (13.1 MB) — h2 is written only at layer-2,
    // long after P2 has consumed ebuf.
    unsigned int* ebuf = (unsigned int*)h2;

    // fused front: coarse histogram + dense1 + starts (no global atomics anywhere)
    fused_front_kernel<<<NB1 + 800 + 400, 256, 0, stream>>>(dstp, hist1, x, W1, htmp,
                                                            batch, starts);
    s1a_kernel<<<NBUCK, 256, 0, stream>>>(hist1, offs, totals);
    s1b_kernel<<<1, 256, 0, stream>>>(totals, bucketStart, rowptr);
    p1_kernel<<<NB1, 256, 0, stream>>>(srcp, dstp, offs, bucketStart, ebuf);
    p2_kernel<<<NBUCK, 256, 0, stream>>>(ebuf, bucketStart, csr_src, rowptr, dinv);

    // layer 1 aggregate (dense1 already done in fused front)
    gcn_agg32v_kernel<<<NN * 8 / 256, 256, 0, stream>>>(rowptr, csr_src, htmp, dinv, b1, h1);

    // layer 2: 32 -> 32
    dense_tile_kernel<32><<<NN / 128, 256, 0, stream>>>(h1, W2, htmp);
    gcn_agg32v_kernel<<<NN * 8 / 256, 256, 0, stream>>>(rowptr, csr_src, htmp, dinv, b2, h2);

    // layer 3: 32 -> 32
    dense_tile_kernel<32><<<NN / 128, 256, 0, stream>>>(h2, W3, htmp);
    gcn_agg32v_kernel<<<NN * 8 / 256, 256, 0, stream>>>(rowptr, csr_src, htmp, dinv, b3, h3);

    // layer 4: 32 -> 1
    dense4_kernel<<<NN / 256, 256, 0, stream>>>(h3, W4, htmp);
    gcn_agg1_kernel<<<NN / 256, 256, 0, stream>>>(rowptr, csr_src, htmp, dinv, b4, h4);

    // fused sort-pool + CNN head
    pool_cnn_kernel<<<NG, 256, 0, stream>>>(h1, h2, h3, h4, starts,
                                            c1w, c1b, c2w, c2b,
                                            l1w, l1b, l2w, l2b, out);
}